// Round 15
// baseline (327.536 us; speedup 1.0000x reference)
//
#include <hip/hip_runtime.h>
#include <stdint.h>

#define D_MODEL 1024
#define T_SEQ   2048
#define BATCH   4
#define NH      16
#define NG      4
#define HD      64

// 0.125 * log2(e): folds softmax scale AND exp->exp2 conversion into Q
#define QSCALE 0.18033688611f

typedef short bf16x8 __attribute__((ext_vector_type(8)));
typedef float f32x4  __attribute__((ext_vector_type(4)));

__device__ __forceinline__ f32x4 mfma16(bf16x8 a, bf16x8 b, f32x4 c) {
    return __builtin_amdgcn_mfma_f32_16x16x32_bf16(a, b, c, 0, 0, 0);
}

// HW bf16 convert (RNE)
__device__ __forceinline__ unsigned short f2bf(float f) {
    __bf16 h = (__bf16)f;
    return __builtin_bit_cast(unsigned short, h);
}

// ---------- cast x (fp32) -> bf16, 4 elems/thread ----------
__global__ void cast_f32_bf16(const float* __restrict__ in,
                              unsigned short* __restrict__ out, int n) {
    int i = (blockIdx.x * blockDim.x + threadIdx.x) * 4;
    if (i < n) {
        float4 v = *reinterpret_cast<const float4*>(in + i);
        ushort4 o;
        o.x = f2bf(v.x); o.y = f2bf(v.y); o.z = f2bf(v.z); o.w = f2bf(v.w);
        *reinterpret_cast<ushort4*>(out + i) = o;
    }
}

// ---------- tiled transpose-cast: in[K][N] fp32 -> out[N][K] bf16 ----------
__global__ __launch_bounds__(256) void transcast(const float* __restrict__ in,
                                                 unsigned short* __restrict__ out,
                                                 int K, int N) {
    __shared__ unsigned short sh[32][33];
    int tx = threadIdx.x & 31, ty = threadIdx.x >> 5;   // 32 x 8
    int n0 = blockIdx.x * 32, k0 = blockIdx.y * 32;
#pragma unroll
    for (int j = 0; j < 4; j++) {
        int k = ty + 8 * j;
        sh[k][tx] = f2bf(in[(size_t)(k0 + k) * N + n0 + tx]);
    }
    __syncthreads();
#pragma unroll
    for (int j = 0; j < 4; j++) {
        int n = ty + 8 * j;
        out[(size_t)(n0 + n) * K + k0 + tx] = sh[tx][n];
    }
}

// ---------- stage one 128x64 bf16 tile: global -> LDS via global_load_lds ----
__device__ __forceinline__ void stage_tile(const unsigned short* __restrict__ src,
                                           unsigned short* lds, int ldK, int tid) {
    int w = tid >> 6;
#pragma unroll
    for (int i = 0; i < 4; i++) {
        int ci  = i * 256 + tid;          // chunk index 0..1023
        int row = ci >> 3, ch = ci & 7;
        int csrc = ch ^ (row & 7);
        const unsigned short* gp = src + (size_t)row * ldK + csrc * 8;
        unsigned short* lp = lds + (size_t)(i * 256 + w * 64) * 8;  // wave-uniform
        __builtin_amdgcn_global_load_lds(
            (const __attribute__((address_space(1))) void*)gp,
            (__attribute__((address_space(3))) void*)lp, 16, 0, 0);
    }
}

// ---------- GEMM m97-style: 128x128 tile, BK=64, 4 waves (2x2) ----------
// MODE 0: fused QKV epilogue (Q scaled by QSCALE; K / Vt scatter layouts).
// MODE 1: fp32 row-major out, bias b0.
template <int MODE>
__global__ __launch_bounds__(256) void gemm128(
        const unsigned short* __restrict__ A,
        const unsigned short* __restrict__ Bt,
        const float* __restrict__ b0, const float* __restrict__ b1,
        const float* __restrict__ b2,
        void* __restrict__ Cq, void* __restrict__ Ck, void* __restrict__ Cv,
        int K) {
    __shared__ unsigned short As[128 * 64];
    __shared__ unsigned short Bs[128 * 64];

    int tid  = threadIdx.x;
    int lane = tid & 63, w = tid >> 6;
    int wr = w >> 1, wc = w & 1;
    int m0 = blockIdx.y * 128, n0 = blockIdx.x * 128;
    int lr = lane & 15, kg = lane >> 4;

    f32x4 acc[4][4] = {};

    const unsigned short* Ab = A  + (size_t)m0 * K;
    const unsigned short* Bb = Bt + (size_t)n0 * K;

    for (int kt = 0; kt < K; kt += 64) {
        stage_tile(Ab + kt, As, K, tid);
        stage_tile(Bb + kt, Bs, K, tid);
        __syncthreads();

        bf16x8 af[4][2], bf[4][2];
#pragma unroll
        for (int mt = 0; mt < 4; mt++) {
            int row = wr * 64 + mt * 16 + lr;
#pragma unroll
            for (int ks = 0; ks < 2; ks++) {
                int ch = (kg + ks * 4) ^ (row & 7);
                af[mt][ks] = *reinterpret_cast<const bf16x8*>(&As[row * 64 + ch * 8]);
            }
        }
#pragma unroll
        for (int nt = 0; nt < 4; nt++) {
            int row = wc * 64 + nt * 16 + lr;
#pragma unroll
            for (int ks = 0; ks < 2; ks++) {
                int ch = (kg + ks * 4) ^ (row & 7);
                bf[nt][ks] = *reinterpret_cast<const bf16x8*>(&Bs[row * 64 + ch * 8]);
            }
        }

#pragma unroll
        for (int ks = 0; ks < 2; ks++)
#pragma unroll
            for (int mt = 0; mt < 4; mt++)
#pragma unroll
                for (int nt = 0; nt < 4; nt++)
                    acc[mt][nt] = mfma16(af[mt][ks], bf[nt][ks], acc[mt][nt]);

        __syncthreads();
    }

    // ---- epilogue ----
    int rbase = kg * 4;
#pragma unroll
    for (int nt = 0; nt < 4; nt++) {
        int col = n0 + wc * 64 + nt * 16 + lr;
        float bias;
        if (MODE == 1)            bias = b0[col];
        else if (col < 1024)      bias = b0[col];
        else if (col < 1280)      bias = b1[col - 1024];
        else                      bias = b2[col - 1280];
#pragma unroll
        for (int mt = 0; mt < 4; mt++) {
#pragma unroll
            for (int r = 0; r < 4; r++) {
                int row = m0 + wr * 64 + mt * 16 + rbase + r;
                float v = acc[mt][nt][r] + bias;
                if (MODE == 1) {
                    ((float*)Cq)[(size_t)row * 1024 + col] = v;
                } else if (col < 1024) {
                    ((unsigned short*)Cq)[(size_t)row * 1024 + col] = f2bf(v * QSCALE);
                } else if (col < 1280) {
                    int cc = col - 1024, g = cc >> 6, d = cc & 63;
                    int b = row >> 11, t = row & 2047;
                    ((unsigned short*)Ck)[(((size_t)(b * NG + g)) * T_SEQ + t) * HD + d] = f2bf(v);
                } else {
                    int cc = col - 1280, g = cc >> 6, d = cc & 63;
                    int b = row >> 11, t = row & 2047;
                    ((unsigned short*)Cv)[(((size_t)(b * NG + g)) * HD + d) * T_SEQ + t] = f2bf(v);
                }
            }
        }
    }
}

// ---------- flash attention v12: v11 structure, V direct from global ----------
// Block = 256 thr = 4 waves; wave w owns q-rows q0 = qt*128 + w*32 (2 x 16).
// K tiles (KVBLK=64) staged in LDS double-buffered via global_load_lds
// (STAGE next || compute current; vmcnt(0)+barrier per tile) -- the K
// prefetch pipeline is what hides HBM/L2 latency (v8 lesson).
// V is NOT staged: fragments read directly from global (L2-resident,
// ~256KB per (b,g)), issued at tile start (T14 issue-early), consumed at
// PV ~400cy later. This removes the V ds_writes AND the 4-way-conflicted
// V b64 ds_reads (8.39M conflict cycles in v11) -- LDS pipe was the
// fullest resource (~50%); V was 2/3 of it. (m169 / common-mistake #7:
// don't LDS-stage what L2 already serves.)
//
// In-register P (validated v7-v11): swapped QK^T s = mfma(K,Q) gives lane
// (q=lr, grp) keys k=16t+4grp+r; transposed PV O^T = mfma(V^T frag, P frag)
// under kappa(8grp+j)=32kh+16(j>>2)+4grp+(j&3) needs exactly the lane's own
// p values. exp2 (scale pre-folded into Q).
// Denominator via ones-A MFMA (validated v10/v11): den = mfma(ones, pf).
// VGPR budget must stay <=128 (v10 lesson: 136 VGPR halved occupancy).
__global__ __launch_bounds__(256) void attn_fwd(
        const unsigned short* __restrict__ Q,
        const unsigned short* __restrict__ Kt,
        const unsigned short* __restrict__ Vt,
        unsigned short* __restrict__ O) {
    int tid  = threadIdx.x;
    int lane = tid & 63;
    int w    = tid >> 6;
    int qt = blockIdx.x, h = blockIdx.y, b = blockIdx.z;
    int g = h >> 2;                 // HPG = 4
    int lr  = lane & 15;
    int grp = lane >> 4;
    int ko  = grp * 8;
    int q0  = qt * 128 + w * 32;

    __shared__ unsigned short Kl[2][64 * 64];

    const unsigned short* Kp = Kt + ((size_t)(b * NG + g)) * T_SEQ * HD;
    const unsigned short* Vp = Vt + ((size_t)(b * NG + g)) * HD * T_SEQ;

    bf16x8 qf[2][2];
#pragma unroll
    for (int qi = 0; qi < 2; qi++) {
        const unsigned short* Qp =
            Q + ((size_t)(b * T_SEQ + q0 + qi * 16 + lr)) * D_MODEL + h * HD;
        qf[qi][0] = *reinterpret_cast<const bf16x8*>(Qp + ko);
        qf[qi][1] = *reinterpret_cast<const bf16x8*>(Qp + 32 + ko);
    }

    f32x4 oacc[2][4] = {};    // [qi][dt] : O^T, col=q=lr, row=d=dt*16+4grp+reg
    f32x4 den[2] = {};        // ones-MFMA denominator (all rows identical)
    bf16x8 ones;
#pragma unroll
    for (int j = 0; j < 8; j++) ones[j] = (short)0x3F80;   // bf16 1.0

    // ---- stage K tile j0 into buffer buf (64 keys x 64 d) ----
    auto STAGE = [&](int buf, int j0) {
#pragma unroll
        for (int i = 0; i < 2; i++) {
            int ci  = i * 256 + tid;          // chunk 0..511
            int row = ci >> 3, ch = ci & 7;
            int csrc = ch ^ (row & 7);
            const unsigned short* gk = Kp + (size_t)(j0 + row) * HD + csrc * 8;
            unsigned short* lk = &Kl[buf][(size_t)(i * 256 + w * 64) * 8];
            __builtin_amdgcn_global_load_lds(
                (const __attribute__((address_space(1))) void*)gk,
                (__attribute__((address_space(3))) void*)lk, 16, 0, 0);
        }
    };

    STAGE(0, 0);
    asm volatile("s_waitcnt vmcnt(0)" ::: "memory");
    __syncthreads();

    int cur = 0;
    for (int jt = 0; jt < T_SEQ / 64; jt++) {
        int j0 = jt * 64;
        if (jt + 1 < T_SEQ / 64) STAGE(cur ^ 1, j0 + 64);

        // ---- V fragments direct from GLOBAL, kappa-ordered (issue early) ----
        // vf[dt][kh]: elems j<4 = Vt[dt*16+lr][j0+kh*32+4grp+j], j>=4 at +16
        bf16x8 vf[4][2];
#pragma unroll
        for (int dt = 0; dt < 4; dt++)
#pragma unroll
            for (int kh = 0; kh < 2; kh++) {
                const unsigned short* vp =
                    Vp + (size_t)(dt * 16 + lr) * T_SEQ + j0 + kh * 32 + 4 * grp;
                short4* halves = reinterpret_cast<short4*>(&vf[dt][kh]);
                halves[0] = *reinterpret_cast<const short4*>(vp);
                halves[1] = *reinterpret_cast<const short4*>(vp + 16);
            }

        // ---- K fragments from LDS (b128, swizzled) ----
        bf16x8 kf[4][2];
#pragma unroll
        for (int t = 0; t < 4; t++) {
            int row = t * 16 + lr;
#pragma unroll
            for (int ks = 0; ks < 2; ks++) {
                int sch = (ks * 4 + grp) ^ (row & 7);
                kf[t][ks] = *reinterpret_cast<const bf16x8*>(&Kl[cur][row * 64 + sch * 8]);
            }
        }

#pragma unroll
        for (int qi = 0; qi < 2; qi++) {
            // ---- S^T = K @ Q (64 keys x 16 q), 8 MFMAs ----
            f32x4 s[4];
            __builtin_amdgcn_s_setprio(1);
#pragma unroll
            for (int t = 0; t < 4; t++) {
                f32x4 a = {};
                a = mfma16(kf[t][0], qf[qi][0], a);
                a = mfma16(kf[t][1], qf[qi][1], a);
                s[t] = a;        // s[t][r] = S[key=16t+4grp+r][q=lr]
            }
            __builtin_amdgcn_s_setprio(0);

            // ---- p = exp2(s) (scale pre-folded into Q) ----
            float p[4][4];
#pragma unroll
            for (int t = 0; t < 4; t++)
#pragma unroll
                for (int r = 0; r < 4; r++)
                    asm("v_exp_f32 %0, %1" : "=v"(p[t][r]) : "v"(s[t][r]));

            // ---- pack P fragments (lane-local, kappa order) ----
            bf16x8 pf0, pf1;
#pragma unroll
            for (int j = 0; j < 4; j++) {
                pf0[j]     = (short)f2bf(p[0][j]);
                pf0[j + 4] = (short)f2bf(p[1][j]);
                pf1[j]     = (short)f2bf(p[2][j]);
                pf1[j + 4] = (short)f2bf(p[3][j]);
            }

            // ---- PV + ones-denominator: 10 MFMAs ----
            __builtin_amdgcn_s_setprio(1);
#pragma unroll
            for (int dt = 0; dt < 4; dt++) {
                oacc[qi][dt] = mfma16(vf[dt][0], pf0, oacc[qi][dt]);
                oacc[qi][dt] = mfma16(vf[dt][1], pf1, oacc[qi][dt]);
            }
            den[qi] = mfma16(ones, pf0, den[qi]);
            den[qi] = mfma16(ones, pf1, den[qi]);
            __builtin_amdgcn_s_setprio(0);
        }

        asm volatile("s_waitcnt vmcnt(0)" ::: "memory");
        __syncthreads();
        cur ^= 1;
    }

    // ---- normalize + write O (den[qi][0] = full row denominator) ----
#pragma unroll
    for (int qi = 0; qi < 2; qi++) {
        float rinv = 1.0f / den[qi][0];
        size_t rowbase = ((size_t)(b * T_SEQ + q0 + qi * 16 + lr)) * D_MODEL + h * HD;
#pragma unroll
        for (int dt = 0; dt < 4; dt++) {
            ushort4 o;
#pragma unroll
            for (int r = 0; r < 4; r++)
                ((unsigned short*)&o)[r] = f2bf(oacc[qi][dt][r] * rinv);
            *reinterpret_cast<ushort4*>(&O[rowbase + dt * 16 + 4 * grp]) = o;
        }
    }
}

extern "C" void kernel_launch(void* const* d_in, const int* in_sizes, int n_in,
                              void* d_out, int out_size, void* d_ws, size_t ws_size,
                              hipStream_t stream) {
    const float* x  = (const float*)d_in[0];
    const float* Wq = (const float*)d_in[1];
    const float* bq = (const float*)d_in[2];
    const float* Wk = (const float*)d_in[3];
    const float* bk = (const float*)d_in[4];
    const float* Wv = (const float*)d_in[5];
    const float* bv = (const float*)d_in[6];
    const float* Wo = (const float*)d_in[7];
    const float* bo = (const float*)d_in[8];

    char* ws = (char*)d_ws;
    // layout (bytes). Wqt|Wkt|Wvt are ADJACENT -> one fused [1536][1024] Bt.
    unsigned short* xb  = (unsigned short*)(ws);             // 16 MB; reused as O
    unsigned short* Wqt = (unsigned short*)(ws + 16777216);  // 2 MB   (rows 0..1023)
    unsigned short* Wkt = (unsigned short*)(ws + 18874368);  // 0.5 MB (rows 1024..1279)
    unsigned short* Wvt = (unsigned short*)(ws + 19398656);  // 0.5 MB (rows 1280..1535)
    unsigned short* Wot = (unsigned short*)(ws + 19922944);  // 2 MB
    unsigned short* Qb  = (unsigned short*)(ws + 22020096);  // 16 MB
    unsigned short* Kb  = (unsigned short*)(ws + 38797312);  // 4 MB
    unsigned short* Vtb = (unsigned short*)(ws + 42991616);  // 4 MB  (total 45 MB)

    const int M = BATCH * T_SEQ;   // 8192

    cast_f32_bf16<<<dim3(M * D_MODEL / 4 / 256), 256, 0, stream>>>(x, xb, M * D_MODEL);
    transcast<<<dim3(32, 32), 256, 0, stream>>>(Wq, Wqt, 1024, 1024);
    transcast<<<dim3(8, 32), 256, 0, stream>>>(Wk, Wkt, 1024, 256);
    transcast<<<dim3(8, 32), 256, 0, stream>>>(Wv, Wvt, 1024, 256);
    transcast<<<dim3(32, 32), 256, 0, stream>>>(Wo, Wot, 1024, 1024);

    // fused QKV projection: [8192][1024] @ [1536][1024]^T
    gemm128<0><<<dim3(12, 64), 256, 0, stream>>>(
        xb, Wqt, bq, bk, bv, Qb, Kb, Vtb, 1024);

    attn_fwd<<<dim3(T_SEQ / 128, NH, BATCH), 256, 0, stream>>>(Qb, Kb, Vtb, xb);

    // output projection -> fp32 d_out
    gemm128<1><<<dim3(8, 64), 256, 0, stream>>>(
        xb, Wot, bo, nullptr, nullptr, d_out, nullptr, nullptr, 1024);
}

// Round 16
// 191.344 us; speedup vs baseline: 1.7118x; 1.7118x over previous
//
#include <hip/hip_runtime.h>
#include <stdint.h>

#define D_MODEL 1024
#define T_SEQ   2048
#define BATCH   4
#define NH      16
#define NG      4
#define HD      64

// 0.125 * log2(e): folds softmax scale AND exp->exp2 conversion into Q
#define QSCALE 0.18033688611f

typedef short bf16x8 __attribute__((ext_vector_type(8)));
typedef float f32x4  __attribute__((ext_vector_type(4)));

__device__ __forceinline__ f32x4 mfma16(bf16x8 a, bf16x8 b, f32x4 c) {
    return __builtin_amdgcn_mfma_f32_16x16x32_bf16(a, b, c, 0, 0, 0);
}

// HW bf16 convert (RNE)
__device__ __forceinline__ unsigned short f2bf(float f) {
    __bf16 h = (__bf16)f;
    return __builtin_bit_cast(unsigned short, h);
}

// ---------- cast x (fp32) -> bf16, 4 elems/thread ----------
__global__ void cast_f32_bf16(const float* __restrict__ in,
                              unsigned short* __restrict__ out, int n) {
    int i = (blockIdx.x * blockDim.x + threadIdx.x) * 4;
    if (i < n) {
        float4 v = *reinterpret_cast<const float4*>(in + i);
        ushort4 o;
        o.x = f2bf(v.x); o.y = f2bf(v.y); o.z = f2bf(v.z); o.w = f2bf(v.w);
        *reinterpret_cast<ushort4*>(out + i) = o;
    }
}

// ---------- tiled transpose-cast: in[K][N] fp32 -> out[N][K] bf16 ----------
__global__ __launch_bounds__(256) void transcast(const float* __restrict__ in,
                                                 unsigned short* __restrict__ out,
                                                 int K, int N) {
    __shared__ unsigned short sh[32][33];
    int tx = threadIdx.x & 31, ty = threadIdx.x >> 5;   // 32 x 8
    int n0 = blockIdx.x * 32, k0 = blockIdx.y * 32;
#pragma unroll
    for (int j = 0; j < 4; j++) {
        int k = ty + 8 * j;
        sh[k][tx] = f2bf(in[(size_t)(k0 + k) * N + n0 + tx]);
    }
    __syncthreads();
#pragma unroll
    for (int j = 0; j < 4; j++) {
        int n = ty + 8 * j;
        out[(size_t)(n0 + n) * K + k0 + tx] = sh[tx][n];
    }
}

// ---------- stage one 128x64 bf16 tile: global -> LDS via global_load_lds ----
__device__ __forceinline__ void stage_tile(const unsigned short* __restrict__ src,
                                           unsigned short* lds, int ldK, int tid) {
    int w = tid >> 6;
#pragma unroll
    for (int i = 0; i < 4; i++) {
        int ci  = i * 256 + tid;          // chunk index 0..1023
        int row = ci >> 3, ch = ci & 7;
        int csrc = ch ^ (row & 7);
        const unsigned short* gp = src + (size_t)row * ldK + csrc * 8;
        unsigned short* lp = lds + (size_t)(i * 256 + w * 64) * 8;  // wave-uniform
        __builtin_amdgcn_global_load_lds(
            (const __attribute__((address_space(1))) void*)gp,
            (__attribute__((address_space(3))) void*)lp, 16, 0, 0);
    }
}

// ---------- GEMM m97-style: 128x128 tile, BK=64, 4 waves (2x2) ----------
// MODE 0: fused QKV epilogue (Q scaled by QSCALE; K / Vt scatter layouts).
// MODE 1: fp32 row-major out, bias b0.
template <int MODE>
__global__ __launch_bounds__(256) void gemm128(
        const unsigned short* __restrict__ A,
        const unsigned short* __restrict__ Bt,
        const float* __restrict__ b0, const float* __restrict__ b1,
        const float* __restrict__ b2,
        void* __restrict__ Cq, void* __restrict__ Ck, void* __restrict__ Cv,
        int K) {
    __shared__ unsigned short As[128 * 64];
    __shared__ unsigned short Bs[128 * 64];

    int tid  = threadIdx.x;
    int lane = tid & 63, w = tid >> 6;
    int wr = w >> 1, wc = w & 1;
    int m0 = blockIdx.y * 128, n0 = blockIdx.x * 128;
    int lr = lane & 15, kg = lane >> 4;

    f32x4 acc[4][4] = {};

    const unsigned short* Ab = A  + (size_t)m0 * K;
    const unsigned short* Bb = Bt + (size_t)n0 * K;

    for (int kt = 0; kt < K; kt += 64) {
        stage_tile(Ab + kt, As, K, tid);
        stage_tile(Bb + kt, Bs, K, tid);
        __syncthreads();

        bf16x8 af[4][2], bf[4][2];
#pragma unroll
        for (int mt = 0; mt < 4; mt++) {
            int row = wr * 64 + mt * 16 + lr;
#pragma unroll
            for (int ks = 0; ks < 2; ks++) {
                int ch = (kg + ks * 4) ^ (row & 7);
                af[mt][ks] = *reinterpret_cast<const bf16x8*>(&As[row * 64 + ch * 8]);
            }
        }
#pragma unroll
        for (int nt = 0; nt < 4; nt++) {
            int row = wc * 64 + nt * 16 + lr;
#pragma unroll
            for (int ks = 0; ks < 2; ks++) {
                int ch = (kg + ks * 4) ^ (row & 7);
                bf[nt][ks] = *reinterpret_cast<const bf16x8*>(&Bs[row * 64 + ch * 8]);
            }
        }

#pragma unroll
        for (int ks = 0; ks < 2; ks++)
#pragma unroll
            for (int mt = 0; mt < 4; mt++)
#pragma unroll
                for (int nt = 0; nt < 4; nt++)
                    acc[mt][nt] = mfma16(af[mt][ks], bf[nt][ks], acc[mt][nt]);

        __syncthreads();
    }

    // ---- epilogue ----
    int rbase = kg * 4;
#pragma unroll
    for (int nt = 0; nt < 4; nt++) {
        int col = n0 + wc * 64 + nt * 16 + lr;
        float bias;
        if (MODE == 1)            bias = b0[col];
        else if (col < 1024)      bias = b0[col];
        else if (col < 1280)      bias = b1[col - 1024];
        else                      bias = b2[col - 1280];
#pragma unroll
        for (int mt = 0; mt < 4; mt++) {
#pragma unroll
            for (int r = 0; r < 4; r++) {
                int row = m0 + wr * 64 + mt * 16 + rbase + r;
                float v = acc[mt][nt][r] + bias;
                if (MODE == 1) {
                    ((float*)Cq)[(size_t)row * 1024 + col] = v;
                } else if (col < 1024) {
                    ((unsigned short*)Cq)[(size_t)row * 1024 + col] = f2bf(v * QSCALE);
                } else if (col < 1280) {
                    int cc = col - 1024, g = cc >> 6, d = cc & 63;
                    int b = row >> 11, t = row & 2047;
                    ((unsigned short*)Ck)[(((size_t)(b * NG + g)) * T_SEQ + t) * HD + d] = f2bf(v);
                } else {
                    int cc = col - 1280, g = cc >> 6, d = cc & 63;
                    int b = row >> 11, t = row & 2047;
                    ((unsigned short*)Cv)[(((size_t)(b * NG + g)) * HD + d) * T_SEQ + t] = f2bf(v);
                }
            }
        }
    }
}

// ---------- flash attention v13: v11 + permuted K rows => b128 V reads ----------
// Block = 256 thr = 4 waves; wave w owns q-rows q0 = qt*128 + w*32 (2 x 16).
// K and V tiles (KVBLK=64) staged in LDS double-buffered via global_load_lds
// (STAGE next || compute current; vmcnt(0)+barrier per tile).
//
// KEY PERMUTATION: K rows staged permuted -- LDS row R holds global key
//   kperm(R) = 32*(R>>5) + 4*((R>>4)&1) + 8*((R>>2)&3) + (R&3)
// (absorbed into the staging SOURCE address, zero extra instructions).
// Then swapped QK^T tile t gives lane (q=lr, grp) reg r the key
//   32*(t>>1) + 4*(t&1) + 8*grp + r  -- i.e. per kh = t>>1 the lane holds
// keys 32kh + 8grp + {0..7}: EIGHT CONTIGUOUS KEYS.
// => PV B-fragment (slot k=8grp+j needs key 32kh+8grp+j) is exactly the
//    lane's own p values: pf_kh[j] = p[t=2kh+(j>>2)][r=j&3] (same pack).
// => V A-fragment is ONE b128 read at key-chunk 4kh+grp (XOR-swizzled),
//    replacing v11's 16 four-way-conflicted b64 reads (8.39M conflict cyc).
// Softmax + ones-MFMA denominator are key-permutation invariant.
// VGPR budget <=128 (v10 lesson). exp2 with scale pre-folded into Q.
__global__ __launch_bounds__(256) void attn_fwd(
        const unsigned short* __restrict__ Q,
        const unsigned short* __restrict__ Kt,
        const unsigned short* __restrict__ Vt,
        unsigned short* __restrict__ O) {
    int tid  = threadIdx.x;
    int lane = tid & 63;
    int w    = tid >> 6;
    int qt = blockIdx.x, h = blockIdx.y, b = blockIdx.z;
    int g = h >> 2;                 // HPG = 4
    int lr  = lane & 15;
    int grp = lane >> 4;
    int ko  = grp * 8;
    int q0  = qt * 128 + w * 32;

    __shared__ unsigned short Kl[2][64 * 64];
    __shared__ unsigned short Vl[2][64 * 64];

    const unsigned short* Kp = Kt + ((size_t)(b * NG + g)) * T_SEQ * HD;
    const unsigned short* Vp = Vt + ((size_t)(b * NG + g)) * HD * T_SEQ;

    bf16x8 qf[2][2];
#pragma unroll
    for (int qi = 0; qi < 2; qi++) {
        const unsigned short* Qp =
            Q + ((size_t)(b * T_SEQ + q0 + qi * 16 + lr)) * D_MODEL + h * HD;
        qf[qi][0] = *reinterpret_cast<const bf16x8*>(Qp + ko);
        qf[qi][1] = *reinterpret_cast<const bf16x8*>(Qp + 32 + ko);
    }

    f32x4 oacc[2][4] = {};    // [qi][dt] : O^T, col=q=lr, row=d=dt*16+4grp+reg
    f32x4 den[2] = {};        // ones-MFMA denominator
    bf16x8 ones;
#pragma unroll
    for (int j = 0; j < 8; j++) ones[j] = (short)0x3F80;   // bf16 1.0

    // ---- stage tile j0: K rows PERMUTED by kperm, V rows linear (d-major) ----
    auto STAGE = [&](int buf, int j0) {
#pragma unroll
        for (int i = 0; i < 2; i++) {
            int ci  = i * 256 + tid;          // chunk 0..511
            int row = ci >> 3, ch = ci & 7;
            int csrc = ch ^ (row & 7);
            // kperm(row): key this LDS row holds
            int kp = 32 * (row >> 5) + 4 * ((row >> 4) & 1)
                   + 8 * ((row >> 2) & 3) + (row & 3);
            const unsigned short* gk = Kp + (size_t)(j0 + kp) * HD + csrc * 8;
            unsigned short* lk = &Kl[buf][(size_t)(i * 256 + w * 64) * 8];
            __builtin_amdgcn_global_load_lds(
                (const __attribute__((address_space(1))) void*)gk,
                (__attribute__((address_space(3))) void*)lk, 16, 0, 0);
            const unsigned short* gv = Vp + (size_t)row * T_SEQ + j0 + csrc * 8;
            unsigned short* lv = &Vl[buf][(size_t)(i * 256 + w * 64) * 8];
            __builtin_amdgcn_global_load_lds(
                (const __attribute__((address_space(1))) void*)gv,
                (__attribute__((address_space(3))) void*)lv, 16, 0, 0);
        }
    };

    STAGE(0, 0);
    asm volatile("s_waitcnt vmcnt(0)" ::: "memory");
    __syncthreads();

    int cur = 0;
    for (int jt = 0; jt < T_SEQ / 64; jt++) {
        if (jt + 1 < T_SEQ / 64) STAGE(cur ^ 1, (jt + 1) * 64);

        // ---- K fragments from LDS (b128, swizzled; rows pre-permuted) ----
        bf16x8 kf[4][2];
#pragma unroll
        for (int t = 0; t < 4; t++) {
            int row = t * 16 + lr;
#pragma unroll
            for (int ks = 0; ks < 2; ks++) {
                int sch = (ks * 4 + grp) ^ (row & 7);
                kf[t][ks] = *reinterpret_cast<const bf16x8*>(&Kl[cur][row * 64 + sch * 8]);
            }
        }
        // ---- V fragments from LDS: ONE b128 per (dt,kh), key-chunk 4kh+grp ----
        bf16x8 vf[4][2];
#pragma unroll
        for (int dt = 0; dt < 4; dt++) {
            int row = dt * 16 + lr;
#pragma unroll
            for (int kh = 0; kh < 2; kh++) {
                int sch = (kh * 4 + grp) ^ (row & 7);
                vf[dt][kh] = *reinterpret_cast<const bf16x8*>(&Vl[cur][row * 64 + sch * 8]);
            }
        }

#pragma unroll
        for (int qi = 0; qi < 2; qi++) {
            // ---- S^T = K @ Q (64 keys x 16 q), 8 MFMAs ----
            f32x4 s[4];
            __builtin_amdgcn_s_setprio(1);
#pragma unroll
            for (int t = 0; t < 4; t++) {
                f32x4 a = {};
                a = mfma16(kf[t][0], qf[qi][0], a);
                a = mfma16(kf[t][1], qf[qi][1], a);
                s[t] = a;   // s[t][r] = S[key=32(t>>1)+4(t&1)+8grp+r][q=lr]
            }
            __builtin_amdgcn_s_setprio(0);

            // ---- p = exp2(s) (scale pre-folded into Q) ----
            float p[4][4];
#pragma unroll
            for (int t = 0; t < 4; t++)
#pragma unroll
                for (int r = 0; r < 4; r++)
                    asm("v_exp_f32 %0, %1" : "=v"(p[t][r]) : "v"(s[t][r]));

            // ---- pack P fragments: pf_kh[j] = p[2kh+(j>>2)][j&3] ----
            bf16x8 pf0, pf1;
#pragma unroll
            for (int j = 0; j < 4; j++) {
                pf0[j]     = (short)f2bf(p[0][j]);
                pf0[j + 4] = (short)f2bf(p[1][j]);
                pf1[j]     = (short)f2bf(p[2][j]);
                pf1[j + 4] = (short)f2bf(p[3][j]);
            }

            // ---- PV + ones-denominator: 10 MFMAs ----
            __builtin_amdgcn_s_setprio(1);
#pragma unroll
            for (int dt = 0; dt < 4; dt++) {
                oacc[qi][dt] = mfma16(vf[dt][0], pf0, oacc[qi][dt]);
                oacc[qi][dt] = mfma16(vf[dt][1], pf1, oacc[qi][dt]);
            }
            den[qi] = mfma16(ones, pf0, den[qi]);
            den[qi] = mfma16(ones, pf1, den[qi]);
            __builtin_amdgcn_s_setprio(0);
        }

        asm volatile("s_waitcnt vmcnt(0)" ::: "memory");
        __syncthreads();
        cur ^= 1;
    }

    // ---- normalize + write O (den[qi][0] = full row denominator) ----
#pragma unroll
    for (int qi = 0; qi < 2; qi++) {
        float rinv = 1.0f / den[qi][0];
        size_t rowbase = ((size_t)(b * T_SEQ + q0 + qi * 16 + lr)) * D_MODEL + h * HD;
#pragma unroll
        for (int dt = 0; dt < 4; dt++) {
            ushort4 o;
#pragma unroll
            for (int r = 0; r < 4; r++)
                ((unsigned short*)&o)[r] = f2bf(oacc[qi][dt][r] * rinv);
            *reinterpret_cast<ushort4*>(&O[rowbase + dt * 16 + 4 * grp]) = o;
        }
    }
}

extern "C" void kernel_launch(void* const* d_in, const int* in_sizes, int n_in,
                              void* d_out, int out_size, void* d_ws, size_t ws_size,
                              hipStream_t stream) {
    const float* x  = (const float*)d_in[0];
    const float* Wq = (const float*)d_in[1];
    const float* bq = (const float*)d_in[2];
    const float* Wk = (const float*)d_in[3];
    const float* bk = (const float*)d_in[4];
    const float* Wv = (const float*)d_in[5];
    const float* bv = (const float*)d_in[6];
    const float* Wo = (const float*)d_in[7];
    const float* bo = (const float*)d_in[8];

    char* ws = (char*)d_ws;
    // layout (bytes). Wqt|Wkt|Wvt are ADJACENT -> one fused [1536][1024] Bt.
    unsigned short* xb  = (unsigned short*)(ws);             // 16 MB; reused as O
    unsigned short* Wqt = (unsigned short*)(ws + 16777216);  // 2 MB   (rows 0..1023)
    unsigned short* Wkt = (unsigned short*)(ws + 18874368);  // 0.5 MB (rows 1024..1279)
    unsigned short* Wvt = (unsigned short*)(ws + 19398656);  // 0.5 MB (rows 1280..1535)
    unsigned short* Wot = (unsigned short*)(ws + 19922944);  // 2 MB
    unsigned short* Qb  = (unsigned short*)(ws + 22020096);  // 16 MB
    unsigned short* Kb  = (unsigned short*)(ws + 38797312);  // 4 MB
    unsigned short* Vtb = (unsigned short*)(ws + 42991616);  // 4 MB  (total 45 MB)

    const int M = BATCH * T_SEQ;   // 8192

    cast_f32_bf16<<<dim3(M * D_MODEL / 4 / 256), 256, 0, stream>>>(x, xb, M * D_MODEL);
    transcast<<<dim3(32, 32), 256, 0, stream>>>(Wq, Wqt, 1024, 1024);
    transcast<<<dim3(8, 32), 256, 0, stream>>>(Wk, Wkt, 1024, 256);
    transcast<<<dim3(8, 32), 256, 0, stream>>>(Wv, Wvt, 1024, 256);
    transcast<<<dim3(32, 32), 256, 0, stream>>>(Wo, Wot, 1024, 1024);

    // fused QKV projection: [8192][1024] @ [1536][1024]^T
    gemm128<0><<<dim3(12, 64), 256, 0, stream>>>(
        xb, Wqt, bq, bk, bv, Qb, Kb, Vtb, 1024);

    attn_fwd<<<dim3(T_SEQ / 128, NH, BATCH), 256, 0, stream>>>(Qb, Kb, Vtb, xb);

    // output projection -> fp32 d_out
    gemm128<1><<<dim3(8, 64), 256, 0, stream>>>(
        xb, Wot, bo, nullptr, nullptr, d_out, nullptr, nullptr, 1024);
}

// Round 17
// 173.602 us; speedup vs baseline: 1.8867x; 1.1022x over previous
//
#include <hip/hip_runtime.h>
#include <stdint.h>

#define D_MODEL 1024
#define T_SEQ   2048
#define BATCH   4
#define NH      16
#define NG      4
#define HD      64

// 0.125 * log2(e): folds softmax scale AND exp->exp2 conversion into Q
#define QSCALE 0.18033688611f

typedef short bf16x8 __attribute__((ext_vector_type(8)));
typedef float f32x4  __attribute__((ext_vector_type(4)));

__device__ __forceinline__ f32x4 mfma16(bf16x8 a, bf16x8 b, f32x4 c) {
    return __builtin_amdgcn_mfma_f32_16x16x32_bf16(a, b, c, 0, 0, 0);
}

// HW bf16 convert (RNE)
__device__ __forceinline__ unsigned short f2bf(float f) {
    __bf16 h = (__bf16)f;
    return __builtin_bit_cast(unsigned short, h);
}

// ---------- fused prep: cast x -> bf16 AND 4 weight transpose-casts ----------
// One launch replaces 5 (saves ~4 graph-replay launch gaps).
// blocks [0, 8192):        cast x (8192*1024 fp32 -> bf16, 4 elems/thread)
// blocks [8192, 8192+2560): transcast tiles (Wq 1024 | Wk 256 | Wv 256 | Wo 1024)
__global__ __launch_bounds__(256) void prep(
        const float* __restrict__ x,  unsigned short* __restrict__ xb,
        const float* __restrict__ Wq, unsigned short* __restrict__ Wqt,
        const float* __restrict__ Wk, unsigned short* __restrict__ Wkt,
        const float* __restrict__ Wv, unsigned short* __restrict__ Wvt,
        const float* __restrict__ Wo, unsigned short* __restrict__ Wot) {
    __shared__ unsigned short sh[32][33];
    int bid = blockIdx.x;
    if (bid < 8192) {
        int i = (bid * 256 + threadIdx.x) * 4;
        float4 v = *reinterpret_cast<const float4*>(x + i);
        ushort4 o;
        o.x = f2bf(v.x); o.y = f2bf(v.y); o.z = f2bf(v.z); o.w = f2bf(v.w);
        *reinterpret_cast<ushort4*>(xb + i) = o;
        return;
    }
    bid -= 8192;
    const float* src; unsigned short* dst; int N, nbx;
    if (bid < 1024)      { src = Wq; dst = Wqt; N = 1024; nbx = 32; }
    else if (bid < 1280) { bid -= 1024; src = Wk; dst = Wkt; N = 256;  nbx = 8; }
    else if (bid < 1536) { bid -= 1280; src = Wv; dst = Wvt; N = 256;  nbx = 8; }
    else                 { bid -= 1536; src = Wo; dst = Wot; N = 1024; nbx = 32; }
    const int K = 1024;
    int n0 = (bid % nbx) * 32, k0 = (bid / nbx) * 32;
    int tx = threadIdx.x & 31, ty = threadIdx.x >> 5;   // 32 x 8
#pragma unroll
    for (int j = 0; j < 4; j++) {
        int k = ty + 8 * j;
        sh[k][tx] = f2bf(src[(size_t)(k0 + k) * N + n0 + tx]);
    }
    __syncthreads();
#pragma unroll
    for (int j = 0; j < 4; j++) {
        int n = ty + 8 * j;
        dst[(size_t)(n0 + n) * K + k0 + tx] = sh[tx][n];
    }
}

// ---------- stage one 128x64 bf16 tile: global -> LDS via global_load_lds ----
__device__ __forceinline__ void stage_tile(const unsigned short* __restrict__ src,
                                           unsigned short* lds, int ldK, int tid) {
    int w = tid >> 6;
#pragma unroll
    for (int i = 0; i < 4; i++) {
        int ci  = i * 256 + tid;          // chunk index 0..1023
        int row = ci >> 3, ch = ci & 7;
        int csrc = ch ^ (row & 7);
        const unsigned short* gp = src + (size_t)row * ldK + csrc * 8;
        unsigned short* lp = lds + (size_t)(i * 256 + w * 64) * 8;  // wave-uniform
        __builtin_amdgcn_global_load_lds(
            (const __attribute__((address_space(1))) void*)gp,
            (__attribute__((address_space(3))) void*)lp, 16, 0, 0);
    }
}

// ---------- GEMM m97-style: 128x128 tile, BK=64, 4 waves (2x2) ----------
// T1 XCD-aware bijective block swizzle (nwg % 8 == 0 for both launches):
// dispatch id L runs on XCD L%8; work id (L%8)*cpx + L/8 gives each XCD a
// CONTIGUOUS chunk of row-major tile space -> A-panel read once per XCD
// instead of 8x from L3.
// MODE 0: fused QKV epilogue (Q scaled by QSCALE; K / Vt scatter layouts).
// MODE 1: fp32 row-major out, bias b0.
template <int MODE>
__global__ __launch_bounds__(256) void gemm128(
        const unsigned short* __restrict__ A,
        const unsigned short* __restrict__ Bt,
        const float* __restrict__ b0, const float* __restrict__ b1,
        const float* __restrict__ b2,
        void* __restrict__ Cq, void* __restrict__ Ck, void* __restrict__ Cv,
        int K) {
    __shared__ unsigned short As[128 * 64];
    __shared__ unsigned short Bs[128 * 64];

    int tid  = threadIdx.x;
    int lane = tid & 63, w = tid >> 6;
    int wr = w >> 1, wc = w & 1;

    // ---- T1 XCD swizzle ----
    int nx  = gridDim.x;
    int lin = blockIdx.y * nx + blockIdx.x;
    int cpx = (nx * gridDim.y) >> 3;          // blocks per XCD (nwg % 8 == 0)
    int nb  = (lin & 7) * cpx + (lin >> 3);
    int m0 = (nb / nx) * 128, n0 = (nb % nx) * 128;

    int lr = lane & 15, kg = lane >> 4;

    f32x4 acc[4][4] = {};

    const unsigned short* Ab = A  + (size_t)m0 * K;
    const unsigned short* Bb = Bt + (size_t)n0 * K;

    for (int kt = 0; kt < K; kt += 64) {
        stage_tile(Ab + kt, As, K, tid);
        stage_tile(Bb + kt, Bs, K, tid);
        __syncthreads();

        bf16x8 af[4][2], bf[4][2];
#pragma unroll
        for (int mt = 0; mt < 4; mt++) {
            int row = wr * 64 + mt * 16 + lr;
#pragma unroll
            for (int ks = 0; ks < 2; ks++) {
                int ch = (kg + ks * 4) ^ (row & 7);
                af[mt][ks] = *reinterpret_cast<const bf16x8*>(&As[row * 64 + ch * 8]);
            }
        }
#pragma unroll
        for (int nt = 0; nt < 4; nt++) {
            int row = wc * 64 + nt * 16 + lr;
#pragma unroll
            for (int ks = 0; ks < 2; ks++) {
                int ch = (kg + ks * 4) ^ (row & 7);
                bf[nt][ks] = *reinterpret_cast<const bf16x8*>(&Bs[row * 64 + ch * 8]);
            }
        }

#pragma unroll
        for (int ks = 0; ks < 2; ks++)
#pragma unroll
            for (int mt = 0; mt < 4; mt++)
#pragma unroll
                for (int nt = 0; nt < 4; nt++)
                    acc[mt][nt] = mfma16(af[mt][ks], bf[nt][ks], acc[mt][nt]);

        __syncthreads();
    }

    // ---- epilogue ----
    int rbase = kg * 4;
#pragma unroll
    for (int nt = 0; nt < 4; nt++) {
        int col = n0 + wc * 64 + nt * 16 + lr;
        float bias;
        if (MODE == 1)            bias = b0[col];
        else if (col < 1024)      bias = b0[col];
        else if (col < 1280)      bias = b1[col - 1024];
        else                      bias = b2[col - 1280];
#pragma unroll
        for (int mt = 0; mt < 4; mt++) {
#pragma unroll
            for (int r = 0; r < 4; r++) {
                int row = m0 + wr * 64 + mt * 16 + rbase + r;
                float v = acc[mt][nt][r] + bias;
                if (MODE == 1) {
                    ((float*)Cq)[(size_t)row * 1024 + col] = v;
                } else if (col < 1024) {
                    ((unsigned short*)Cq)[(size_t)row * 1024 + col] = f2bf(v * QSCALE);
                } else if (col < 1280) {
                    int cc = col - 1024, g = cc >> 6, d = cc & 63;
                    int b = row >> 11, t = row & 2047;
                    ((unsigned short*)Ck)[(((size_t)(b * NG + g)) * T_SEQ + t) * HD + d] = f2bf(v);
                } else {
                    int cc = col - 1280, g = cc >> 6, d = cc & 63;
                    int b = row >> 11, t = row & 2047;
                    ((unsigned short*)Cv)[(((size_t)(b * NG + g)) * HD + d) * T_SEQ + t] = f2bf(v);
                }
            }
        }
    }
}

// ---------- flash attention v13 (best; unchanged from round 16) ----------
// Block = 256 thr = 4 waves; wave w owns q-rows q0 = qt*128 + w*32 (2 x 16).
// K and V tiles (KVBLK=64) staged in LDS double-buffered via global_load_lds.
// K rows staged PERMUTED by kperm => PV B-fragment is lane-local and the V
// A-fragment is ONE b128 swizzled read (0 bank conflicts, round-16 verified).
// exp2 with scale pre-folded into Q; ones-MFMA denominator; VGPR 96.
__global__ __launch_bounds__(256) void attn_fwd(
        const unsigned short* __restrict__ Q,
        const unsigned short* __restrict__ Kt,
        const unsigned short* __restrict__ Vt,
        unsigned short* __restrict__ O) {
    int tid  = threadIdx.x;
    int lane = tid & 63;
    int w    = tid >> 6;
    int qt = blockIdx.x, h = blockIdx.y, b = blockIdx.z;
    int g = h >> 2;                 // HPG = 4
    int lr  = lane & 15;
    int grp = lane >> 4;
    int ko  = grp * 8;
    int q0  = qt * 128 + w * 32;

    __shared__ unsigned short Kl[2][64 * 64];
    __shared__ unsigned short Vl[2][64 * 64];

    const unsigned short* Kp = Kt + ((size_t)(b * NG + g)) * T_SEQ * HD;
    const unsigned short* Vp = Vt + ((size_t)(b * NG + g)) * HD * T_SEQ;

    bf16x8 qf[2][2];
#pragma unroll
    for (int qi = 0; qi < 2; qi++) {
        const unsigned short* Qp =
            Q + ((size_t)(b * T_SEQ + q0 + qi * 16 + lr)) * D_MODEL + h * HD;
        qf[qi][0] = *reinterpret_cast<const bf16x8*>(Qp + ko);
        qf[qi][1] = *reinterpret_cast<const bf16x8*>(Qp + 32 + ko);
    }

    f32x4 oacc[2][4] = {};    // [qi][dt] : O^T, col=q=lr, row=d=dt*16+4grp+reg
    f32x4 den[2] = {};        // ones-MFMA denominator
    bf16x8 ones;
#pragma unroll
    for (int j = 0; j < 8; j++) ones[j] = (short)0x3F80;   // bf16 1.0

    auto STAGE = [&](int buf, int j0) {
#pragma unroll
        for (int i = 0; i < 2; i++) {
            int ci  = i * 256 + tid;          // chunk 0..511
            int row = ci >> 3, ch = ci & 7;
            int csrc = ch ^ (row & 7);
            int kp = 32 * (row >> 5) + 4 * ((row >> 4) & 1)
                   + 8 * ((row >> 2) & 3) + (row & 3);
            const unsigned short* gk = Kp + (size_t)(j0 + kp) * HD + csrc * 8;
            unsigned short* lk = &Kl[buf][(size_t)(i * 256 + w * 64) * 8];
            __builtin_amdgcn_global_load_lds(
                (const __attribute__((address_space(1))) void*)gk,
                (__attribute__((address_space(3))) void*)lk, 16, 0, 0);
            const unsigned short* gv = Vp + (size_t)row * T_SEQ + j0 + csrc * 8;
            unsigned short* lv = &Vl[buf][(size_t)(i * 256 + w * 64) * 8];
            __builtin_amdgcn_global_load_lds(
                (const __attribute__((address_space(1))) void*)gv,
                (__attribute__((address_space(3))) void*)lv, 16, 0, 0);
        }
    };

    STAGE(0, 0);
    asm volatile("s_waitcnt vmcnt(0)" ::: "memory");
    __syncthreads();

    int cur = 0;
    for (int jt = 0; jt < T_SEQ / 64; jt++) {
        if (jt + 1 < T_SEQ / 64) STAGE(cur ^ 1, (jt + 1) * 64);

        bf16x8 kf[4][2];
#pragma unroll
        for (int t = 0; t < 4; t++) {
            int row = t * 16 + lr;
#pragma unroll
            for (int ks = 0; ks < 2; ks++) {
                int sch = (ks * 4 + grp) ^ (row & 7);
                kf[t][ks] = *reinterpret_cast<const bf16x8*>(&Kl[cur][row * 64 + sch * 8]);
            }
        }
        bf16x8 vf[4][2];
#pragma unroll
        for (int dt = 0; dt < 4; dt++) {
            int row = dt * 16 + lr;
#pragma unroll
            for (int kh = 0; kh < 2; kh++) {
                int sch = (kh * 4 + grp) ^ (row & 7);
                vf[dt][kh] = *reinterpret_cast<const bf16x8*>(&Vl[cur][row * 64 + sch * 8]);
            }
        }

#pragma unroll
        for (int qi = 0; qi < 2; qi++) {
            f32x4 s[4];
            __builtin_amdgcn_s_setprio(1);
#pragma unroll
            for (int t = 0; t < 4; t++) {
                f32x4 a = {};
                a = mfma16(kf[t][0], qf[qi][0], a);
                a = mfma16(kf[t][1], qf[qi][1], a);
                s[t] = a;   // s[t][r] = S[key=32(t>>1)+4(t&1)+8grp+r][q=lr]
            }
            __builtin_amdgcn_s_setprio(0);

            float p[4][4];
#pragma unroll
            for (int t = 0; t < 4; t++)
#pragma unroll
                for (int r = 0; r < 4; r++)
                    asm("v_exp_f32 %0, %1" : "=v"(p[t][r]) : "v"(s[t][r]));

            bf16x8 pf0, pf1;
#pragma unroll
            for (int j = 0; j < 4; j++) {
                pf0[j]     = (short)f2bf(p[0][j]);
                pf0[j + 4] = (short)f2bf(p[1][j]);
                pf1[j]     = (short)f2bf(p[2][j]);
                pf1[j + 4] = (short)f2bf(p[3][j]);
            }

            __builtin_amdgcn_s_setprio(1);
#pragma unroll
            for (int dt = 0; dt < 4; dt++) {
                oacc[qi][dt] = mfma16(vf[dt][0], pf0, oacc[qi][dt]);
                oacc[qi][dt] = mfma16(vf[dt][1], pf1, oacc[qi][dt]);
            }
            den[qi] = mfma16(ones, pf0, den[qi]);
            den[qi] = mfma16(ones, pf1, den[qi]);
            __builtin_amdgcn_s_setprio(0);
        }

        asm volatile("s_waitcnt vmcnt(0)" ::: "memory");
        __syncthreads();
        cur ^= 1;
    }

#pragma unroll
    for (int qi = 0; qi < 2; qi++) {
        float rinv = 1.0f / den[qi][0];
        size_t rowbase = ((size_t)(b * T_SEQ + q0 + qi * 16 + lr)) * D_MODEL + h * HD;
#pragma unroll
        for (int dt = 0; dt < 4; dt++) {
            ushort4 o;
#pragma unroll
            for (int r = 0; r < 4; r++)
                ((unsigned short*)&o)[r] = f2bf(oacc[qi][dt][r] * rinv);
            *reinterpret_cast<ushort4*>(&O[rowbase + dt * 16 + 4 * grp]) = o;
        }
    }
}

extern "C" void kernel_launch(void* const* d_in, const int* in_sizes, int n_in,
                              void* d_out, int out_size, void* d_ws, size_t ws_size,
                              hipStream_t stream) {
    const float* x  = (const float*)d_in[0];
    const float* Wq = (const float*)d_in[1];
    const float* bq = (const float*)d_in[2];
    const float* Wk = (const float*)d_in[3];
    const float* bk = (const float*)d_in[4];
    const float* Wv = (const float*)d_in[5];
    const float* bv = (const float*)d_in[6];
    const float* Wo = (const float*)d_in[7];
    const float* bo = (const float*)d_in[8];

    char* ws = (char*)d_ws;
    // layout (bytes). Wqt|Wkt|Wvt are ADJACENT -> one fused [1536][1024] Bt.
    unsigned short* xb  = (unsigned short*)(ws);             // 16 MB; reused as O
    unsigned short* Wqt = (unsigned short*)(ws + 16777216);  // 2 MB   (rows 0..1023)
    unsigned short* Wkt = (unsigned short*)(ws + 18874368);  // 0.5 MB (rows 1024..1279)
    unsigned short* Wvt = (unsigned short*)(ws + 19398656);  // 0.5 MB (rows 1280..1535)
    unsigned short* Wot = (unsigned short*)(ws + 19922944);  // 2 MB
    unsigned short* Qb  = (unsigned short*)(ws + 22020096);  // 16 MB
    unsigned short* Kb  = (unsigned short*)(ws + 38797312);  // 4 MB
    unsigned short* Vtb = (unsigned short*)(ws + 42991616);  // 4 MB  (total 45 MB)

    // fused prep: cast x + 4 weight transcasts in ONE launch
    prep<<<dim3(8192 + 2560), 256, 0, stream>>>(
        x, xb, Wq, Wqt, Wk, Wkt, Wv, Wvt, Wo, Wot);

    // fused QKV projection: [8192][1024] @ [1536][1024]^T  (768 blocks, %8==0)
    gemm128<0><<<dim3(12, 64), 256, 0, stream>>>(
        xb, Wqt, bq, bk, bv, Qb, Kb, Vtb, 1024);

    attn_fwd<<<dim3(T_SEQ / 128, NH, BATCH), 256, 0, stream>>>(Qb, Kb, Vtb, xb);

    // output projection -> fp32 d_out  (512 blocks, %8==0)
    gemm128<1><<<dim3(8, 64), 256, 0, stream>>>(
        xb, Wot, bo, nullptr, nullptr, d_out, nullptr, nullptr, 1024);
}

// Round 18
// 162.362 us; speedup vs baseline: 2.0173x; 1.0692x over previous
//
#include <hip/hip_runtime.h>
#include <stdint.h>

#define D_MODEL 1024
#define T_SEQ   2048
#define BATCH   4
#define NH      16
#define NG      4
#define HD      64

// 0.125 * log2(e): folds softmax scale AND exp->exp2 conversion into Q
#define QSCALE 0.18033688611f

typedef short bf16x8 __attribute__((ext_vector_type(8)));
typedef float f32x4  __attribute__((ext_vector_type(4)));

__device__ __forceinline__ f32x4 mfma16(bf16x8 a, bf16x8 b, f32x4 c) {
    return __builtin_amdgcn_mfma_f32_16x16x32_bf16(a, b, c, 0, 0, 0);
}

// HW bf16 convert (RNE)
__device__ __forceinline__ unsigned short f2bf(float f) {
    __bf16 h = (__bf16)f;
    return __builtin_bit_cast(unsigned short, h);
}

// ---------- fused prep: cast x -> bf16 AND 4 weight transpose-casts ----------
__global__ __launch_bounds__(256) void prep(
        const float* __restrict__ x,  unsigned short* __restrict__ xb,
        const float* __restrict__ Wq, unsigned short* __restrict__ Wqt,
        const float* __restrict__ Wk, unsigned short* __restrict__ Wkt,
        const float* __restrict__ Wv, unsigned short* __restrict__ Wvt,
        const float* __restrict__ Wo, unsigned short* __restrict__ Wot) {
    __shared__ unsigned short sh[32][33];
    int bid = blockIdx.x;
    if (bid < 8192) {
        int i = (bid * 256 + threadIdx.x) * 4;
        float4 v = *reinterpret_cast<const float4*>(x + i);
        ushort4 o;
        o.x = f2bf(v.x); o.y = f2bf(v.y); o.z = f2bf(v.z); o.w = f2bf(v.w);
        *reinterpret_cast<ushort4*>(xb + i) = o;
        return;
    }
    bid -= 8192;
    const float* src; unsigned short* dst; int N, nbx;
    if (bid < 1024)      { src = Wq; dst = Wqt; N = 1024; nbx = 32; }
    else if (bid < 1280) { bid -= 1024; src = Wk; dst = Wkt; N = 256;  nbx = 8; }
    else if (bid < 1536) { bid -= 1280; src = Wv; dst = Wvt; N = 256;  nbx = 8; }
    else                 { bid -= 1536; src = Wo; dst = Wot; N = 1024; nbx = 32; }
    const int K = 1024;
    int n0 = (bid % nbx) * 32, k0 = (bid / nbx) * 32;
    int tx = threadIdx.x & 31, ty = threadIdx.x >> 5;   // 32 x 8
#pragma unroll
    for (int j = 0; j < 4; j++) {
        int k = ty + 8 * j;
        sh[k][tx] = f2bf(src[(size_t)(k0 + k) * N + n0 + tx]);
    }
    __syncthreads();
#pragma unroll
    for (int j = 0; j < 4; j++) {
        int n = ty + 8 * j;
        dst[(size_t)(n0 + n) * K + k0 + tx] = sh[tx][n];
    }
}

// ---------- stage one 128x64 bf16 tile: global -> LDS via global_load_lds ----
__device__ __forceinline__ void stage_tile(const unsigned short* __restrict__ src,
                                           unsigned short* lds, int ldK, int tid) {
    int w = tid >> 6;
#pragma unroll
    for (int i = 0; i < 4; i++) {
        int ci  = i * 256 + tid;          // chunk index 0..1023
        int row = ci >> 3, ch = ci & 7;
        int csrc = ch ^ (row & 7);
        const unsigned short* gp = src + (size_t)row * ldK + csrc * 8;
        unsigned short* lp = lds + (size_t)(i * 256 + w * 64) * 8;  // wave-uniform
        __builtin_amdgcn_global_load_lds(
            (const __attribute__((address_space(1))) void*)gp,
            (__attribute__((address_space(3))) void*)lp, 16, 0, 0);
    }
}

// ---------- GEMM m97-style: 128x128 tile, BK=64, 4 waves (2x2) ----------
// T1 XCD-aware bijective block swizzle (nwg % 8 == 0 for both launches).
// MODE 0: fused QKV epilogue (Q scaled by QSCALE; K / Vt scatter layouts).
// MODE 1: fp32 row-major out, bias b0.
template <int MODE>
__global__ __launch_bounds__(256) void gemm128(
        const unsigned short* __restrict__ A,
        const unsigned short* __restrict__ Bt,
        const float* __restrict__ b0, const float* __restrict__ b1,
        const float* __restrict__ b2,
        void* __restrict__ Cq, void* __restrict__ Ck, void* __restrict__ Cv,
        int K) {
    __shared__ unsigned short As[128 * 64];
    __shared__ unsigned short Bs[128 * 64];

    int tid  = threadIdx.x;
    int lane = tid & 63, w = tid >> 6;
    int wr = w >> 1, wc = w & 1;

    // ---- T1 XCD swizzle ----
    int nx  = gridDim.x;
    int lin = blockIdx.y * nx + blockIdx.x;
    int cpx = (nx * gridDim.y) >> 3;          // blocks per XCD (nwg % 8 == 0)
    int nb  = (lin & 7) * cpx + (lin >> 3);
    int m0 = (nb / nx) * 128, n0 = (nb % nx) * 128;

    int lr = lane & 15, kg = lane >> 4;

    f32x4 acc[4][4] = {};

    const unsigned short* Ab = A  + (size_t)m0 * K;
    const unsigned short* Bb = Bt + (size_t)n0 * K;

    for (int kt = 0; kt < K; kt += 64) {
        stage_tile(Ab + kt, As, K, tid);
        stage_tile(Bb + kt, Bs, K, tid);
        __syncthreads();

        bf16x8 af[4][2], bf[4][2];
#pragma unroll
        for (int mt = 0; mt < 4; mt++) {
            int row = wr * 64 + mt * 16 + lr;
#pragma unroll
            for (int ks = 0; ks < 2; ks++) {
                int ch = (kg + ks * 4) ^ (row & 7);
                af[mt][ks] = *reinterpret_cast<const bf16x8*>(&As[row * 64 + ch * 8]);
            }
        }
#pragma unroll
        for (int nt = 0; nt < 4; nt++) {
            int row = wc * 64 + nt * 16 + lr;
#pragma unroll
            for (int ks = 0; ks < 2; ks++) {
                int ch = (kg + ks * 4) ^ (row & 7);
                bf[nt][ks] = *reinterpret_cast<const bf16x8*>(&Bs[row * 64 + ch * 8]);
            }
        }

#pragma unroll
        for (int ks = 0; ks < 2; ks++)
#pragma unroll
            for (int mt = 0; mt < 4; mt++)
#pragma unroll
                for (int nt = 0; nt < 4; nt++)
                    acc[mt][nt] = mfma16(af[mt][ks], bf[nt][ks], acc[mt][nt]);

        __syncthreads();
    }

    // ---- epilogue ----
    int rbase = kg * 4;
#pragma unroll
    for (int nt = 0; nt < 4; nt++) {
        int col = n0 + wc * 64 + nt * 16 + lr;
        float bias;
        if (MODE == 1)            bias = b0[col];
        else if (col < 1024)      bias = b0[col];
        else if (col < 1280)      bias = b1[col - 1024];
        else                      bias = b2[col - 1280];
#pragma unroll
        for (int mt = 0; mt < 4; mt++) {
#pragma unroll
            for (int r = 0; r < 4; r++) {
                int row = m0 + wr * 64 + mt * 16 + rbase + r;
                float v = acc[mt][nt][r] + bias;
                if (MODE == 1) {
                    ((float*)Cq)[(size_t)row * 1024 + col] = v;
                } else if (col < 1024) {
                    ((unsigned short*)Cq)[(size_t)row * 1024 + col] = f2bf(v * QSCALE);
                } else if (col < 1280) {
                    int cc = col - 1024, g = cc >> 6, d = cc & 63;
                    int b = row >> 11, t = row & 2047;
                    ((unsigned short*)Ck)[(((size_t)(b * NG + g)) * T_SEQ + t) * HD + d] = f2bf(v);
                } else {
                    int cc = col - 1280, g = cc >> 6, d = cc & 63;
                    int b = row >> 11, t = row & 2047;
                    ((unsigned short*)Cv)[(((size_t)(b * NG + g)) * HD + d) * T_SEQ + t] = f2bf(v);
                }
            }
        }
    }
}

// ---------- flash attention v14: v13 + hoisted LDS offsets, literal cur ----------
// Block = 256 thr = 4 waves; wave w owns q-rows q0 = qt*128 + w*32 (2 x 16).
// K/V tiles (KVBLK=64) staged in LDS double-buffered via global_load_lds;
// K rows staged PERMUTED by kperm => PV B-fragment lane-local, V A-fragment
// one b128 swizzled read (0 bank conflicts, round-16 verified).
//
// v14 change (single variable): the per-lane LDS read offsets
//   loff[c][s] = row*64 + (((s*4+grp)^(row&7))*8), row = c*16+lr
// are IDENTICAL for K and V reads and loop-invariant. Hoist them into 8
// VGPRs before the loop, and unroll jt by 2 so `cur` is a compile-time
// literal (Kl[1] at fixed +4096 elements -> folds into ds_read offset).
// Removes ~60-80 recomputed address-VALU ops per wave-tile (~equal to the
// entire exp block) from the busiest pipe (VALUBusy 47%).
__global__ __launch_bounds__(256) void attn_fwd(
        const unsigned short* __restrict__ Q,
        const unsigned short* __restrict__ Kt,
        const unsigned short* __restrict__ Vt,
        unsigned short* __restrict__ O) {
    int tid  = threadIdx.x;
    int lane = tid & 63;
    int w    = tid >> 6;
    int qt = blockIdx.x, h = blockIdx.y, b = blockIdx.z;
    int g = h >> 2;                 // HPG = 4
    int lr  = lane & 15;
    int grp = lane >> 4;
    int ko  = grp * 8;
    int q0  = qt * 128 + w * 32;

    __shared__ unsigned short Kl[2][64 * 64];
    __shared__ unsigned short Vl[2][64 * 64];

    const unsigned short* Kp = Kt + ((size_t)(b * NG + g)) * T_SEQ * HD;
    const unsigned short* Vp = Vt + ((size_t)(b * NG + g)) * HD * T_SEQ;

    bf16x8 qf[2][2];
#pragma unroll
    for (int qi = 0; qi < 2; qi++) {
        const unsigned short* Qp =
            Q + ((size_t)(b * T_SEQ + q0 + qi * 16 + lr)) * D_MODEL + h * HD;
        qf[qi][0] = *reinterpret_cast<const bf16x8*>(Qp + ko);
        qf[qi][1] = *reinterpret_cast<const bf16x8*>(Qp + 32 + ko);
    }

    f32x4 oacc[2][4] = {};    // [qi][dt] : O^T, col=q=lr, row=d=dt*16+4grp+reg
    f32x4 den[2] = {};        // ones-MFMA denominator
    bf16x8 ones;
#pragma unroll
    for (int j = 0; j < 8; j++) ones[j] = (short)0x3F80;   // bf16 1.0

    // ---- hoisted LDS read offsets (elements); same formula for K and V ----
    int loff[4][2];
#pragma unroll
    for (int c = 0; c < 4; c++) {
        int row = c * 16 + lr;
#pragma unroll
        for (int s = 0; s < 2; s++)
            loff[c][s] = row * 64 + (((s * 4 + grp) ^ (row & 7)) * 8);
    }

    auto STAGE = [&](int buf, int j0) {
#pragma unroll
        for (int i = 0; i < 2; i++) {
            int ci  = i * 256 + tid;          // chunk 0..511
            int row = ci >> 3, ch = ci & 7;
            int csrc = ch ^ (row & 7);
            int kp = 32 * (row >> 5) + 4 * ((row >> 4) & 1)
                   + 8 * ((row >> 2) & 3) + (row & 3);
            const unsigned short* gk = Kp + (size_t)(j0 + kp) * HD + csrc * 8;
            unsigned short* lk = &Kl[buf][(size_t)(i * 256 + w * 64) * 8];
            __builtin_amdgcn_global_load_lds(
                (const __attribute__((address_space(1))) void*)gk,
                (__attribute__((address_space(3))) void*)lk, 16, 0, 0);
            const unsigned short* gv = Vp + (size_t)row * T_SEQ + j0 + csrc * 8;
            unsigned short* lv = &Vl[buf][(size_t)(i * 256 + w * 64) * 8];
            __builtin_amdgcn_global_load_lds(
                (const __attribute__((address_space(1))) void*)gv,
                (__attribute__((address_space(3))) void*)lv, 16, 0, 0);
        }
    };

    // ---- one tile: cur is a COMPILE-TIME literal at each call site ----
    auto do_tile = [&](int cur, int jt) {
        if (jt + 1 < T_SEQ / 64) STAGE(cur ^ 1, (jt + 1) * 64);

        const unsigned short* kb = &Kl[cur][0];
        const unsigned short* vb = &Vl[cur][0];

        bf16x8 kf[4][2], vf[4][2];
#pragma unroll
        for (int t = 0; t < 4; t++)
#pragma unroll
            for (int ks = 0; ks < 2; ks++)
                kf[t][ks] = *reinterpret_cast<const bf16x8*>(kb + loff[t][ks]);
#pragma unroll
        for (int dt = 0; dt < 4; dt++)
#pragma unroll
            for (int kh = 0; kh < 2; kh++)
                vf[dt][kh] = *reinterpret_cast<const bf16x8*>(vb + loff[dt][kh]);

#pragma unroll
        for (int qi = 0; qi < 2; qi++) {
            f32x4 s[4];
            __builtin_amdgcn_s_setprio(1);
#pragma unroll
            for (int t = 0; t < 4; t++) {
                f32x4 a = {};
                a = mfma16(kf[t][0], qf[qi][0], a);
                a = mfma16(kf[t][1], qf[qi][1], a);
                s[t] = a;   // s[t][r] = S[key=32(t>>1)+4(t&1)+8grp+r][q=lr]
            }
            __builtin_amdgcn_s_setprio(0);

            float p[4][4];
#pragma unroll
            for (int t = 0; t < 4; t++)
#pragma unroll
                for (int r = 0; r < 4; r++)
                    asm("v_exp_f32 %0, %1" : "=v"(p[t][r]) : "v"(s[t][r]));

            bf16x8 pf0, pf1;
#pragma unroll
            for (int j = 0; j < 4; j++) {
                pf0[j]     = (short)f2bf(p[0][j]);
                pf0[j + 4] = (short)f2bf(p[1][j]);
                pf1[j]     = (short)f2bf(p[2][j]);
                pf1[j + 4] = (short)f2bf(p[3][j]);
            }

            __builtin_amdgcn_s_setprio(1);
#pragma unroll
            for (int dt = 0; dt < 4; dt++) {
                oacc[qi][dt] = mfma16(vf[dt][0], pf0, oacc[qi][dt]);
                oacc[qi][dt] = mfma16(vf[dt][1], pf1, oacc[qi][dt]);
            }
            den[qi] = mfma16(ones, pf0, den[qi]);
            den[qi] = mfma16(ones, pf1, den[qi]);
            __builtin_amdgcn_s_setprio(0);
        }

        asm volatile("s_waitcnt vmcnt(0)" ::: "memory");
        __syncthreads();
    };

    STAGE(0, 0);
    asm volatile("s_waitcnt vmcnt(0)" ::: "memory");
    __syncthreads();

    for (int jt = 0; jt < T_SEQ / 64; jt += 2) {
        do_tile(0, jt);       // literal cur=0
        do_tile(1, jt + 1);   // literal cur=1
    }

    // ---- normalize + write O (den[qi][0] = full row denominator) ----
#pragma unroll
    for (int qi = 0; qi < 2; qi++) {
        float rinv = 1.0f / den[qi][0];
        size_t rowbase = ((size_t)(b * T_SEQ + q0 + qi * 16 + lr)) * D_MODEL + h * HD;
#pragma unroll
        for (int dt = 0; dt < 4; dt++) {
            ushort4 o;
#pragma unroll
            for (int r = 0; r < 4; r++)
                ((unsigned short*)&o)[r] = f2bf(oacc[qi][dt][r] * rinv);
            *reinterpret_cast<ushort4*>(&O[rowbase + dt * 16 + 4 * grp]) = o;
        }
    }
}

extern "C" void kernel_launch(void* const* d_in, const int* in_sizes, int n_in,
                              void* d_out, int out_size, void* d_ws, size_t ws_size,
                              hipStream_t stream) {
    const float* x  = (const float*)d_in[0];
    const float* Wq = (const float*)d_in[1];
    const float* bq = (const float*)d_in[2];
    const float* Wk = (const float*)d_in[3];
    const float* bk = (const float*)d_in[4];
    const float* Wv = (const float*)d_in[5];
    const float* bv = (const float*)d_in[6];
    const float* Wo = (const float*)d_in[7];
    const float* bo = (const float*)d_in[8];

    char* ws = (char*)d_ws;
    // layout (bytes). Wqt|Wkt|Wvt are ADJACENT -> one fused [1536][1024] Bt.
    unsigned short* xb  = (unsigned short*)(ws);             // 16 MB; reused as O
    unsigned short* Wqt = (unsigned short*)(ws + 16777216);  // 2 MB   (rows 0..1023)
    unsigned short* Wkt = (unsigned short*)(ws + 18874368);  // 0.5 MB (rows 1024..1279)
    unsigned short* Wvt = (unsigned short*)(ws + 19398656);  // 0.5 MB (rows 1280..1535)
    unsigned short* Wot = (unsigned short*)(ws + 19922944);  // 2 MB
    unsigned short* Qb  = (unsigned short*)(ws + 22020096);  // 16 MB
    unsigned short* Kb  = (unsigned short*)(ws + 38797312);  // 4 MB
    unsigned short* Vtb = (unsigned short*)(ws + 42991616);  // 4 MB  (total 45 MB)

    // fused prep: cast x + 4 weight transcasts in ONE launch
    prep<<<dim3(8192 + 2560), 256, 0, stream>>>(
        x, xb, Wq, Wqt, Wk, Wkt, Wv, Wvt, Wo, Wot);

    // fused QKV projection: [8192][1024] @ [1536][1024]^T  (768 blocks, %8==0)
    gemm128<0><<<dim3(12, 64), 256, 0, stream>>>(
        xb, Wqt, bq, bk, bv, Qb, Kb, Vtb, 1024);

    attn_fwd<<<dim3(T_SEQ / 128, NH, BATCH), 256, 0, stream>>>(Qb, Kb, Vtb, xb);

    // output projection -> fp32 d_out  (512 blocks, %8==0)
    gemm128<1><<<dim3(8, 64), 256, 0, stream>>>(
        xb, Wot, bo, nullptr, nullptr, d_out, nullptr, nullptr, 1024);
}

// Round 19
// 162.354 us; speedup vs baseline: 2.0174x; 1.0000x over previous
//
#include <hip/hip_runtime.h>
#include <stdint.h>

#define D_MODEL 1024
#define T_SEQ   2048
#define BATCH   4
#define NH      16
#define NG      4
#define HD      64

// 0.125 * log2(e): folds softmax scale AND exp->exp2 conversion into Q
#define QSCALE 0.18033688611f

typedef short bf16x8 __attribute__((ext_vector_type(8)));
typedef float f32x4  __attribute__((ext_vector_type(4)));

__device__ __forceinline__ f32x4 mfma16(bf16x8 a, bf16x8 b, f32x4 c) {
    return __builtin_amdgcn_mfma_f32_16x16x32_bf16(a, b, c, 0, 0, 0);
}

// HW bf16 convert (RNE)
__device__ __forceinline__ unsigned short f2bf(float f) {
    __bf16 h = (__bf16)f;
    return __builtin_bit_cast(unsigned short, h);
}

// ---------- fused prep: cast x -> bf16 AND 4 weight transpose-casts ----------
__global__ __launch_bounds__(256) void prep(
        const float* __restrict__ x,  unsigned short* __restrict__ xb,
        const float* __restrict__ Wq, unsigned short* __restrict__ Wqt,
        const float* __restrict__ Wk, unsigned short* __restrict__ Wkt,
        const float* __restrict__ Wv, unsigned short* __restrict__ Wvt,
        const float* __restrict__ Wo, unsigned short* __restrict__ Wot) {
    __shared__ unsigned short sh[32][33];
    int bid = blockIdx.x;
    if (bid < 8192) {
        int i = (bid * 256 + threadIdx.x) * 4;
        float4 v = *reinterpret_cast<const float4*>(x + i);
        ushort4 o;
        o.x = f2bf(v.x); o.y = f2bf(v.y); o.z = f2bf(v.z); o.w = f2bf(v.w);
        *reinterpret_cast<ushort4*>(xb + i) = o;
        return;
    }
    bid -= 8192;
    const float* src; unsigned short* dst; int N, nbx;
    if (bid < 1024)      { src = Wq; dst = Wqt; N = 1024; nbx = 32; }
    else if (bid < 1280) { bid -= 1024; src = Wk; dst = Wkt; N = 256;  nbx = 8; }
    else if (bid < 1536) { bid -= 1280; src = Wv; dst = Wvt; N = 256;  nbx = 8; }
    else                 { bid -= 1536; src = Wo; dst = Wot; N = 1024; nbx = 32; }
    const int K = 1024;
    int n0 = (bid % nbx) * 32, k0 = (bid / nbx) * 32;
    int tx = threadIdx.x & 31, ty = threadIdx.x >> 5;   // 32 x 8
#pragma unroll
    for (int j = 0; j < 4; j++) {
        int k = ty + 8 * j;
        sh[k][tx] = f2bf(src[(size_t)(k0 + k) * N + n0 + tx]);
    }
    __syncthreads();
#pragma unroll
    for (int j = 0; j < 4; j++) {
        int n = ty + 8 * j;
        dst[(size_t)(n0 + n) * K + k0 + tx] = sh[tx][n];
    }
}

// ---------- GEMM m97-style: 128x128 tile, BK=64, 4 waves (2x2) ----------
// T1 XCD-aware bijective block swizzle (nwg % 8 == 0 for both launches).
// v15: staging addresses hoisted -- per-lane soff[i] = row*K + csrc*8 and
// the LDS destinations are K-loop invariant; per K-step only +kt is added.
// MODE 0: fused QKV epilogue (Q scaled by QSCALE; K / Vt scatter layouts).
// MODE 1: fp32 row-major out, bias b0.
template <int MODE>
__global__ __launch_bounds__(256) void gemm128(
        const unsigned short* __restrict__ A,
        const unsigned short* __restrict__ Bt,
        const float* __restrict__ b0, const float* __restrict__ b1,
        const float* __restrict__ b2,
        void* __restrict__ Cq, void* __restrict__ Ck, void* __restrict__ Cv,
        int K) {
    __shared__ unsigned short As[128 * 64];
    __shared__ unsigned short Bs[128 * 64];

    int tid  = threadIdx.x;
    int lane = tid & 63, w = tid >> 6;
    int wr = w >> 1, wc = w & 1;

    // ---- T1 XCD swizzle ----
    int nx  = gridDim.x;
    int lin = blockIdx.y * nx + blockIdx.x;
    int cpx = (nx * gridDim.y) >> 3;          // blocks per XCD (nwg % 8 == 0)
    int nb  = (lin & 7) * cpx + (lin >> 3);
    int m0 = (nb / nx) * 128, n0 = (nb % nx) * 128;

    int lr = lane & 15, kg = lane >> 4;

    f32x4 acc[4][4] = {};

    const unsigned short* Ab = A  + (size_t)m0 * K;
    const unsigned short* Bb = Bt + (size_t)n0 * K;

    // ---- hoisted staging offsets (K-loop invariant) ----
    size_t soff[4];
    unsigned short* adst[4];
    unsigned short* bdst[4];
#pragma unroll
    for (int i = 0; i < 4; i++) {
        int ci  = i * 256 + tid;          // chunk index 0..1023
        int row = ci >> 3, ch = ci & 7;
        int csrc = ch ^ (row & 7);
        soff[i] = (size_t)row * K + csrc * 8;
        adst[i] = As + (size_t)(i * 256 + w * 64) * 8;   // wave-uniform
        bdst[i] = Bs + (size_t)(i * 256 + w * 64) * 8;
    }

    for (int kt = 0; kt < K; kt += 64) {
#pragma unroll
        for (int i = 0; i < 4; i++) {
            __builtin_amdgcn_global_load_lds(
                (const __attribute__((address_space(1))) void*)(Ab + soff[i] + kt),
                (__attribute__((address_space(3))) void*)adst[i], 16, 0, 0);
            __builtin_amdgcn_global_load_lds(
                (const __attribute__((address_space(1))) void*)(Bb + soff[i] + kt),
                (__attribute__((address_space(3))) void*)bdst[i], 16, 0, 0);
        }
        __syncthreads();

        bf16x8 af[4][2], bf[4][2];
#pragma unroll
        for (int mt = 0; mt < 4; mt++) {
            int row = wr * 64 + mt * 16 + lr;
#pragma unroll
            for (int ks = 0; ks < 2; ks++) {
                int ch = (kg + ks * 4) ^ (row & 7);
                af[mt][ks] = *reinterpret_cast<const bf16x8*>(&As[row * 64 + ch * 8]);
            }
        }
#pragma unroll
        for (int nt = 0; nt < 4; nt++) {
            int row = wc * 64 + nt * 16 + lr;
#pragma unroll
            for (int ks = 0; ks < 2; ks++) {
                int ch = (kg + ks * 4) ^ (row & 7);
                bf[nt][ks] = *reinterpret_cast<const bf16x8*>(&Bs[row * 64 + ch * 8]);
            }
        }

#pragma unroll
        for (int ks = 0; ks < 2; ks++)
#pragma unroll
            for (int mt = 0; mt < 4; mt++)
#pragma unroll
                for (int nt = 0; nt < 4; nt++)
                    acc[mt][nt] = mfma16(af[mt][ks], bf[nt][ks], acc[mt][nt]);

        __syncthreads();
    }

    // ---- epilogue ----
    int rbase = kg * 4;
#pragma unroll
    for (int nt = 0; nt < 4; nt++) {
        int col = n0 + wc * 64 + nt * 16 + lr;
        float bias;
        if (MODE == 1)            bias = b0[col];
        else if (col < 1024)      bias = b0[col];
        else if (col < 1280)      bias = b1[col - 1024];
        else                      bias = b2[col - 1280];
#pragma unroll
        for (int mt = 0; mt < 4; mt++) {
#pragma unroll
            for (int r = 0; r < 4; r++) {
                int row = m0 + wr * 64 + mt * 16 + rbase + r;
                float v = acc[mt][nt][r] + bias;
                if (MODE == 1) {
                    ((float*)Cq)[(size_t)row * 1024 + col] = v;
                } else if (col < 1024) {
                    ((unsigned short*)Cq)[(size_t)row * 1024 + col] = f2bf(v * QSCALE);
                } else if (col < 1280) {
                    int cc = col - 1024, g = cc >> 6, d = cc & 63;
                    int b = row >> 11, t = row & 2047;
                    ((unsigned short*)Ck)[(((size_t)(b * NG + g)) * T_SEQ + t) * HD + d] = f2bf(v);
                } else {
                    int cc = col - 1280, g = cc >> 6, d = cc & 63;
                    int b = row >> 11, t = row & 2047;
                    ((unsigned short*)Cv)[(((size_t)(b * NG + g)) * HD + d) * T_SEQ + t] = f2bf(v);
                }
            }
        }
    }
}

// ---------- flash attention v15: v14 + hoisted STAGE addressing ----------
// Block = 256 thr = 4 waves; wave w owns q-rows q0 = qt*128 + w*32 (2 x 16).
// K/V tiles (KVBLK=64) staged in LDS double-buffered via global_load_lds;
// K rows staged PERMUTED by kperm => PV B-fragment lane-local, V A-fragment
// one b128 swizzled read (0 bank conflicts). Hoisted LDS read offsets +
// literal cur (v14). v15: STAGE's per-lane global base pointers hoisted --
//   gkb[i] = Kp + kperm*HD + csrc*8  (STAGE adds j0*HD = j0<<6)
//   gvb[i] = Vp + row*T_SEQ + csrc*8 (STAGE adds j0)
// removing ~20-30 recomputed VALU ops per tile from the busiest pipe.
__global__ __launch_bounds__(256) void attn_fwd(
        const unsigned short* __restrict__ Q,
        const unsigned short* __restrict__ Kt,
        const unsigned short* __restrict__ Vt,
        unsigned short* __restrict__ O) {
    int tid  = threadIdx.x;
    int lane = tid & 63;
    int w    = tid >> 6;
    int qt = blockIdx.x, h = blockIdx.y, b = blockIdx.z;
    int g = h >> 2;                 // HPG = 4
    int lr  = lane & 15;
    int grp = lane >> 4;
    int ko  = grp * 8;
    int q0  = qt * 128 + w * 32;

    __shared__ unsigned short Kl[2][64 * 64];
    __shared__ unsigned short Vl[2][64 * 64];

    const unsigned short* Kp = Kt + ((size_t)(b * NG + g)) * T_SEQ * HD;
    const unsigned short* Vp = Vt + ((size_t)(b * NG + g)) * HD * T_SEQ;

    bf16x8 qf[2][2];
#pragma unroll
    for (int qi = 0; qi < 2; qi++) {
        const unsigned short* Qp =
            Q + ((size_t)(b * T_SEQ + q0 + qi * 16 + lr)) * D_MODEL + h * HD;
        qf[qi][0] = *reinterpret_cast<const bf16x8*>(Qp + ko);
        qf[qi][1] = *reinterpret_cast<const bf16x8*>(Qp + 32 + ko);
    }

    f32x4 oacc[2][4] = {};    // [qi][dt] : O^T, col=q=lr, row=d=dt*16+4grp+reg
    f32x4 den[2] = {};        // ones-MFMA denominator
    bf16x8 ones;
#pragma unroll
    for (int j = 0; j < 8; j++) ones[j] = (short)0x3F80;   // bf16 1.0

    // ---- hoisted LDS read offsets (elements); same formula for K and V ----
    int loff[4][2];
#pragma unroll
    for (int c = 0; c < 4; c++) {
        int row = c * 16 + lr;
#pragma unroll
        for (int s = 0; s < 2; s++)
            loff[c][s] = row * 64 + (((s * 4 + grp) ^ (row & 7)) * 8);
    }

    // ---- hoisted STAGE global bases + LDS dests (tile-loop invariant) ----
    const unsigned short* gkb[2];
    const unsigned short* gvb[2];
    unsigned short* lkd[2];   // LDS dest within a buffer (buf offset = 4096 elems)
#pragma unroll
    for (int i = 0; i < 2; i++) {
        int ci  = i * 256 + tid;          // chunk 0..511
        int row = ci >> 3, ch = ci & 7;
        int csrc = ch ^ (row & 7);
        int kp = 32 * (row >> 5) + 4 * ((row >> 4) & 1)
               + 8 * ((row >> 2) & 3) + (row & 3);
        gkb[i] = Kp + (size_t)kp * HD + csrc * 8;
        gvb[i] = Vp + (size_t)row * T_SEQ + csrc * 8;
        lkd[i] = (unsigned short*)((size_t)(i * 256 + w * 64) * 8);  // elem offset
    }

    auto STAGE = [&](int buf, int j0) {
#pragma unroll
        for (int i = 0; i < 2; i++) {
            size_t ldoff = (size_t)lkd[i];
            __builtin_amdgcn_global_load_lds(
                (const __attribute__((address_space(1))) void*)(gkb[i] + ((size_t)j0 << 6)),
                (__attribute__((address_space(3))) void*)(&Kl[buf][0] + ldoff), 16, 0, 0);
            __builtin_amdgcn_global_load_lds(
                (const __attribute__((address_space(1))) void*)(gvb[i] + j0),
                (__attribute__((address_space(3))) void*)(&Vl[buf][0] + ldoff), 16, 0, 0);
        }
    };

    // ---- one tile: cur is a COMPILE-TIME literal at each call site ----
    auto do_tile = [&](int cur, int jt) {
        if (jt + 1 < T_SEQ / 64) STAGE(cur ^ 1, (jt + 1) * 64);

        const unsigned short* kb = &Kl[cur][0];
        const unsigned short* vb = &Vl[cur][0];

        bf16x8 kf[4][2], vf[4][2];
#pragma unroll
        for (int t = 0; t < 4; t++)
#pragma unroll
            for (int ks = 0; ks < 2; ks++)
                kf[t][ks] = *reinterpret_cast<const bf16x8*>(kb + loff[t][ks]);
#pragma unroll
        for (int dt = 0; dt < 4; dt++)
#pragma unroll
            for (int kh = 0; kh < 2; kh++)
                vf[dt][kh] = *reinterpret_cast<const bf16x8*>(vb + loff[dt][kh]);

#pragma unroll
        for (int qi = 0; qi < 2; qi++) {
            f32x4 s[4];
            __builtin_amdgcn_s_setprio(1);
#pragma unroll
            for (int t = 0; t < 4; t++) {
                f32x4 a = {};
                a = mfma16(kf[t][0], qf[qi][0], a);
                a = mfma16(kf[t][1], qf[qi][1], a);
                s[t] = a;   // s[t][r] = S[key=32(t>>1)+4(t&1)+8grp+r][q=lr]
            }
            __builtin_amdgcn_s_setprio(0);

            float p[4][4];
#pragma unroll
            for (int t = 0; t < 4; t++)
#pragma unroll
                for (int r = 0; r < 4; r++)
                    asm("v_exp_f32 %0, %1" : "=v"(p[t][r]) : "v"(s[t][r]));

            bf16x8 pf0, pf1;
#pragma unroll
            for (int j = 0; j < 4; j++) {
                pf0[j]     = (short)f2bf(p[0][j]);
                pf0[j + 4] = (short)f2bf(p[1][j]);
                pf1[j]     = (short)f2bf(p[2][j]);
                pf1[j + 4] = (short)f2bf(p[3][j]);
            }

            __builtin_amdgcn_s_setprio(1);
#pragma unroll
            for (int dt = 0; dt < 4; dt++) {
                oacc[qi][dt] = mfma16(vf[dt][0], pf0, oacc[qi][dt]);
                oacc[qi][dt] = mfma16(vf[dt][1], pf1, oacc[qi][dt]);
            }
            den[qi] = mfma16(ones, pf0, den[qi]);
            den[qi] = mfma16(ones, pf1, den[qi]);
            __builtin_amdgcn_s_setprio(0);
        }

        asm volatile("s_waitcnt vmcnt(0)" ::: "memory");
        __syncthreads();
    };

    STAGE(0, 0);
    asm volatile("s_waitcnt vmcnt(0)" ::: "memory");
    __syncthreads();

    for (int jt = 0; jt < T_SEQ / 64; jt += 2) {
        do_tile(0, jt);       // literal cur=0
        do_tile(1, jt + 1);   // literal cur=1
    }

    // ---- normalize + write O (den[qi][0] = full row denominator) ----
#pragma unroll
    for (int qi = 0; qi < 2; qi++) {
        float rinv = 1.0f / den[qi][0];
        size_t rowbase = ((size_t)(b * T_SEQ + q0 + qi * 16 + lr)) * D_MODEL + h * HD;
#pragma unroll
        for (int dt = 0; dt < 4; dt++) {
            ushort4 o;
#pragma unroll
            for (int r = 0; r < 4; r++)
                ((unsigned short*)&o)[r] = f2bf(oacc[qi][dt][r] * rinv);
            *reinterpret_cast<ushort4*>(&O[rowbase + dt * 16 + 4 * grp]) = o;
        }
    }
}

extern "C" void kernel_launch(void* const* d_in, const int* in_sizes, int n_in,
                              void* d_out, int out_size, void* d_ws, size_t ws_size,
                              hipStream_t stream) {
    const float* x  = (const float*)d_in[0];
    const float* Wq = (const float*)d_in[1];
    const float* bq = (const float*)d_in[2];
    const float* Wk = (const float*)d_in[3];
    const float* bk = (const float*)d_in[4];
    const float* Wv = (const float*)d_in[5];
    const float* bv = (const float*)d_in[6];
    const float* Wo = (const float*)d_in[7];
    const float* bo = (const float*)d_in[8];

    char* ws = (char*)d_ws;
    // layout (bytes). Wqt|Wkt|Wvt are ADJACENT -> one fused [1536][1024] Bt.
    unsigned short* xb  = (unsigned short*)(ws);             // 16 MB; reused as O
    unsigned short* Wqt = (unsigned short*)(ws + 16777216);  // 2 MB   (rows 0..1023)
    unsigned short* Wkt = (unsigned short*)(ws + 18874368);  // 0.5 MB (rows 1024..1279)
    unsigned short* Wvt = (unsigned short*)(ws + 19398656);  // 0.5 MB (rows 1280..1535)
    unsigned short* Wot = (unsigned short*)(ws + 19922944);  // 2 MB
    unsigned short* Qb  = (unsigned short*)(ws + 22020096);  // 16 MB
    unsigned short* Kb  = (unsigned short*)(ws + 38797312);  // 4 MB
    unsigned short* Vtb = (unsigned short*)(ws + 42991616);  // 4 MB  (total 45 MB)

    // fused prep: cast x + 4 weight transcasts in ONE launch
    prep<<<dim3(8192 + 2560), 256, 0, stream>>>(
        x, xb, Wq, Wqt, Wk, Wkt, Wv, Wvt, Wo, Wot);

    // fused QKV projection: [8192][1024] @ [1536][1024]^T  (768 blocks, %8==0)
    gemm128<0><<<dim3(12, 64), 256, 0, stream>>>(
        xb, Wqt, bq, bk, bv, Qb, Kb, Vtb, 1024);

    attn_fwd<<<dim3(T_SEQ / 128, NH, BATCH), 256, 0, stream>>>(Qb, Kb, Vtb, xb);

    // output projection -> fp32 d_out  (512 blocks, %8==0)
    gemm128<1><<<dim3(8, 64), 256, 0, stream>>>(
        xb, Wot, bo, nullptr, nullptr, d_out, nullptr, nullptr, 1024);
}

// Round 20
// 161.576 us; speedup vs baseline: 2.0271x; 1.0048x over previous
//
#include <hip/hip_runtime.h>
#include <stdint.h>

#define D_MODEL 1024
#define T_SEQ   2048
#define BATCH   4
#define NH      16
#define NG      4
#define HD      64

// 0.125 * log2(e): folds softmax scale AND exp->exp2 conversion into Q
#define QSCALE 0.18033688611f

typedef short bf16x8 __attribute__((ext_vector_type(8)));
typedef float f32x4  __attribute__((ext_vector_type(4)));

__device__ __forceinline__ f32x4 mfma16(bf16x8 a, bf16x8 b, f32x4 c) {
    return __builtin_amdgcn_mfma_f32_16x16x32_bf16(a, b, c, 0, 0, 0);
}

// HW bf16 convert (RNE)
__device__ __forceinline__ unsigned short f2bf(float f) {
    __bf16 h = (__bf16)f;
    return __builtin_bit_cast(unsigned short, h);
}

// ---------- fused prep: cast x -> bf16 AND 4 weight transpose-casts ----------
__global__ __launch_bounds__(256) void prep(
        const float* __restrict__ x,  unsigned short* __restrict__ xb,
        const float* __restrict__ Wq, unsigned short* __restrict__ Wqt,
        const float* __restrict__ Wk, unsigned short* __restrict__ Wkt,
        const float* __restrict__ Wv, unsigned short* __restrict__ Wvt,
        const float* __restrict__ Wo, unsigned short* __restrict__ Wot) {
    __shared__ unsigned short sh[32][33];
    int bid = blockIdx.x;
    if (bid < 8192) {
        int i = (bid * 256 + threadIdx.x) * 4;
        float4 v = *reinterpret_cast<const float4*>(x + i);
        ushort4 o;
        o.x = f2bf(v.x); o.y = f2bf(v.y); o.z = f2bf(v.z); o.w = f2bf(v.w);
        *reinterpret_cast<ushort4*>(xb + i) = o;
        return;
    }
    bid -= 8192;
    const float* src; unsigned short* dst; int N, nbx;
    if (bid < 1024)      { src = Wq; dst = Wqt; N = 1024; nbx = 32; }
    else if (bid < 1280) { bid -= 1024; src = Wk; dst = Wkt; N = 256;  nbx = 8; }
    else if (bid < 1536) { bid -= 1280; src = Wv; dst = Wvt; N = 256;  nbx = 8; }
    else                 { bid -= 1536; src = Wo; dst = Wot; N = 1024; nbx = 32; }
    const int K = 1024;
    int n0 = (bid % nbx) * 32, k0 = (bid / nbx) * 32;
    int tx = threadIdx.x & 31, ty = threadIdx.x >> 5;   // 32 x 8
#pragma unroll
    for (int j = 0; j < 4; j++) {
        int k = ty + 8 * j;
        sh[k][tx] = f2bf(src[(size_t)(k0 + k) * N + n0 + tx]);
    }
    __syncthreads();
#pragma unroll
    for (int j = 0; j < 4; j++) {
        int n = ty + 8 * j;
        dst[(size_t)(n0 + n) * K + k0 + tx] = sh[tx][n];
    }
}

// ---------- GEMM m97-style: 128x128 tile, BK=64, 4 waves (2x2) ----------
// T1 XCD-aware bijective block swizzle (nwg % 8 == 0 for both launches).
// Hoisted staging offsets; per K-step only +kt is added.
// MODE 0: fused QKV epilogue (Q scaled by QSCALE; K / Vt scatter layouts).
// MODE 1: fp32 row-major out, bias b0.
template <int MODE>
__global__ __launch_bounds__(256) void gemm128(
        const unsigned short* __restrict__ A,
        const unsigned short* __restrict__ Bt,
        const float* __restrict__ b0, const float* __restrict__ b1,
        const float* __restrict__ b2,
        void* __restrict__ Cq, void* __restrict__ Ck, void* __restrict__ Cv,
        int K) {
    __shared__ unsigned short As[128 * 64];
    __shared__ unsigned short Bs[128 * 64];

    int tid  = threadIdx.x;
    int lane = tid & 63, w = tid >> 6;
    int wr = w >> 1, wc = w & 1;

    // ---- T1 XCD swizzle ----
    int nx  = gridDim.x;
    int lin = blockIdx.y * nx + blockIdx.x;
    int cpx = (nx * gridDim.y) >> 3;          // blocks per XCD (nwg % 8 == 0)
    int nb  = (lin & 7) * cpx + (lin >> 3);
    int m0 = (nb / nx) * 128, n0 = (nb % nx) * 128;

    int lr = lane & 15, kg = lane >> 4;

    f32x4 acc[4][4] = {};

    const unsigned short* Ab = A  + (size_t)m0 * K;
    const unsigned short* Bb = Bt + (size_t)n0 * K;

    // ---- hoisted staging offsets (K-loop invariant) ----
    size_t soff[4];
    unsigned short* adst[4];
    unsigned short* bdst[4];
#pragma unroll
    for (int i = 0; i < 4; i++) {
        int ci  = i * 256 + tid;          // chunk index 0..1023
        int row = ci >> 3, ch = ci & 7;
        int csrc = ch ^ (row & 7);
        soff[i] = (size_t)row * K + csrc * 8;
        adst[i] = As + (size_t)(i * 256 + w * 64) * 8;   // wave-uniform
        bdst[i] = Bs + (size_t)(i * 256 + w * 64) * 8;
    }

    for (int kt = 0; kt < K; kt += 64) {
#pragma unroll
        for (int i = 0; i < 4; i++) {
            __builtin_amdgcn_global_load_lds(
                (const __attribute__((address_space(1))) void*)(Ab + soff[i] + kt),
                (__attribute__((address_space(3))) void*)adst[i], 16, 0, 0);
            __builtin_amdgcn_global_load_lds(
                (const __attribute__((address_space(1))) void*)(Bb + soff[i] + kt),
                (__attribute__((address_space(3))) void*)bdst[i], 16, 0, 0);
        }
        __syncthreads();

        bf16x8 af[4][2], bf[4][2];
#pragma unroll
        for (int mt = 0; mt < 4; mt++) {
            int row = wr * 64 + mt * 16 + lr;
#pragma unroll
            for (int ks = 0; ks < 2; ks++) {
                int ch = (kg + ks * 4) ^ (row & 7);
                af[mt][ks] = *reinterpret_cast<const bf16x8*>(&As[row * 64 + ch * 8]);
            }
        }
#pragma unroll
        for (int nt = 0; nt < 4; nt++) {
            int row = wc * 64 + nt * 16 + lr;
#pragma unroll
            for (int ks = 0; ks < 2; ks++) {
                int ch = (kg + ks * 4) ^ (row & 7);
                bf[nt][ks] = *reinterpret_cast<const bf16x8*>(&Bs[row * 64 + ch * 8]);
            }
        }

#pragma unroll
        for (int ks = 0; ks < 2; ks++)
#pragma unroll
            for (int mt = 0; mt < 4; mt++)
#pragma unroll
                for (int nt = 0; nt < 4; nt++)
                    acc[mt][nt] = mfma16(af[mt][ks], bf[nt][ks], acc[mt][nt]);

        __syncthreads();
    }

    // ---- epilogue ----
    int rbase = kg * 4;
#pragma unroll
    for (int nt = 0; nt < 4; nt++) {
        int col = n0 + wc * 64 + nt * 16 + lr;
        float bias;
        if (MODE == 1)            bias = b0[col];
        else if (col < 1024)      bias = b0[col];
        else if (col < 1280)      bias = b1[col - 1024];
        else                      bias = b2[col - 1280];
#pragma unroll
        for (int mt = 0; mt < 4; mt++) {
#pragma unroll
            for (int r = 0; r < 4; r++) {
                int row = m0 + wr * 64 + mt * 16 + rbase + r;
                float v = acc[mt][nt][r] + bias;
                if (MODE == 1) {
                    ((float*)Cq)[(size_t)row * 1024 + col] = v;
                } else if (col < 1024) {
                    ((unsigned short*)Cq)[(size_t)row * 1024 + col] = f2bf(v * QSCALE);
                } else if (col < 1280) {
                    int cc = col - 1024, g = cc >> 6, d = cc & 63;
                    int b = row >> 11, t = row & 2047;
                    ((unsigned short*)Ck)[(((size_t)(b * NG + g)) * T_SEQ + t) * HD + d] = f2bf(v);
                } else {
                    int cc = col - 1280, g = cc >> 6, d = cc & 63;
                    int b = row >> 11, t = row & 2047;
                    ((unsigned short*)Cv)[(((size_t)(b * NG + g)) * HD + d) * T_SEQ + t] = f2bf(v);
                }
            }
        }
    }
}

// ---------- flash attention v16: triple-buffer + counted vmcnt (T4) ----------
// v14/v15 structure (kperm'd K staging, lane-local P, b128 V reads, hoisted
// LDS offsets) with the tile-end sync changed from {vmcnt(0)+__syncthreads}
// (drains the just-issued next-tile loads -> the ~19% neither-pipe-issuing
// stall) to the T4 pattern:
//   - 3 K/V buffers; tile jt stages tile jt+2 -> each stage has TWO tiles
//     (~1100 cy) of compute to land (covers ~900 cy HBM-miss latency).
//   - tile end: asm vmcnt(4) (its own 4 newest loads may stay in flight;
//     the 4 for tile jt+1 must have landed) + RAW s_barrier (no compiler
//     vmcnt(0) drain), bracketed by compiler memory fences so no ds_read
//     crosses the barrier.
//   - tiles 30/31 stage nothing; tile-30 end waits vmcnt(0).
// Buffer-overwrite safety: stage into (jt+2)%3 overwrites tile jt-1's
// buffer, whose readers all finished before the end-of-(jt-1) barrier.
// Cost: LDS 32->48 KB (3 blocks/CU instead of 4) -- betting drain removal
// beats the 25% TLP loss.
__global__ __launch_bounds__(256) void attn_fwd(
        const unsigned short* __restrict__ Q,
        const unsigned short* __restrict__ Kt,
        const unsigned short* __restrict__ Vt,
        unsigned short* __restrict__ O) {
    int tid  = threadIdx.x;
    int lane = tid & 63;
    int w    = tid >> 6;
    int qt = blockIdx.x, h = blockIdx.y, b = blockIdx.z;
    int g = h >> 2;                 // HPG = 4
    int lr  = lane & 15;
    int grp = lane >> 4;
    int ko  = grp * 8;
    int q0  = qt * 128 + w * 32;

    __shared__ unsigned short Kl[3][64 * 64];
    __shared__ unsigned short Vl[3][64 * 64];

    const unsigned short* Kp = Kt + ((size_t)(b * NG + g)) * T_SEQ * HD;
    const unsigned short* Vp = Vt + ((size_t)(b * NG + g)) * HD * T_SEQ;

    bf16x8 qf[2][2];
#pragma unroll
    for (int qi = 0; qi < 2; qi++) {
        const unsigned short* Qp =
            Q + ((size_t)(b * T_SEQ + q0 + qi * 16 + lr)) * D_MODEL + h * HD;
        qf[qi][0] = *reinterpret_cast<const bf16x8*>(Qp + ko);
        qf[qi][1] = *reinterpret_cast<const bf16x8*>(Qp + 32 + ko);
    }

    f32x4 oacc[2][4] = {};    // [qi][dt] : O^T, col=q=lr, row=d=dt*16+4grp+reg
    f32x4 den[2] = {};        // ones-MFMA denominator
    bf16x8 ones;
#pragma unroll
    for (int j = 0; j < 8; j++) ones[j] = (short)0x3F80;   // bf16 1.0

    // ---- hoisted LDS read offsets (elements); same formula for K and V ----
    int loff[4][2];
#pragma unroll
    for (int c = 0; c < 4; c++) {
        int row = c * 16 + lr;
#pragma unroll
        for (int s = 0; s < 2; s++)
            loff[c][s] = row * 64 + (((s * 4 + grp) ^ (row & 7)) * 8);
    }

    // ---- hoisted STAGE global bases + LDS dest offset ----
    const unsigned short* gkb[2];
    const unsigned short* gvb[2];
    size_t lkd[2];
#pragma unroll
    for (int i = 0; i < 2; i++) {
        int ci  = i * 256 + tid;          // chunk 0..511
        int row = ci >> 3, ch = ci & 7;
        int csrc = ch ^ (row & 7);
        int kp = 32 * (row >> 5) + 4 * ((row >> 4) & 1)
               + 8 * ((row >> 2) & 3) + (row & 3);
        gkb[i] = Kp + (size_t)kp * HD + csrc * 8;
        gvb[i] = Vp + (size_t)row * T_SEQ + csrc * 8;
        lkd[i] = (size_t)(i * 256 + w * 64) * 8;  // elem offset within buffer
    }

    auto STAGE = [&](int buf, int j0) {   // buf literal at every call site
#pragma unroll
        for (int i = 0; i < 2; i++) {
            __builtin_amdgcn_global_load_lds(
                (const __attribute__((address_space(1))) void*)(gkb[i] + ((size_t)j0 << 6)),
                (__attribute__((address_space(3))) void*)(&Kl[buf][0] + lkd[i]), 16, 0, 0);
            __builtin_amdgcn_global_load_lds(
                (const __attribute__((address_space(1))) void*)(gvb[i] + j0),
                (__attribute__((address_space(3))) void*)(&Vl[buf][0] + lkd[i]), 16, 0, 0);
        }
    };

    // ---- compute body for tile in buffer `cur` (literal) ----
    auto COMPUTE = [&](int cur) {
        const unsigned short* kb = &Kl[cur][0];
        const unsigned short* vb = &Vl[cur][0];

        bf16x8 kf[4][2], vf[4][2];
#pragma unroll
        for (int t = 0; t < 4; t++)
#pragma unroll
            for (int ks = 0; ks < 2; ks++)
                kf[t][ks] = *reinterpret_cast<const bf16x8*>(kb + loff[t][ks]);
#pragma unroll
        for (int dt = 0; dt < 4; dt++)
#pragma unroll
            for (int kh = 0; kh < 2; kh++)
                vf[dt][kh] = *reinterpret_cast<const bf16x8*>(vb + loff[dt][kh]);

#pragma unroll
        for (int qi = 0; qi < 2; qi++) {
            f32x4 s[4];
            __builtin_amdgcn_s_setprio(1);
#pragma unroll
            for (int t = 0; t < 4; t++) {
                f32x4 a = {};
                a = mfma16(kf[t][0], qf[qi][0], a);
                a = mfma16(kf[t][1], qf[qi][1], a);
                s[t] = a;   // s[t][r] = S[key=32(t>>1)+4(t&1)+8grp+r][q=lr]
            }
            __builtin_amdgcn_s_setprio(0);

            float p[4][4];
#pragma unroll
            for (int t = 0; t < 4; t++)
#pragma unroll
                for (int r = 0; r < 4; r++)
                    asm("v_exp_f32 %0, %1" : "=v"(p[t][r]) : "v"(s[t][r]));

            bf16x8 pf0, pf1;
#pragma unroll
            for (int j = 0; j < 4; j++) {
                pf0[j]     = (short)f2bf(p[0][j]);
                pf0[j + 4] = (short)f2bf(p[1][j]);
                pf1[j]     = (short)f2bf(p[2][j]);
                pf1[j + 4] = (short)f2bf(p[3][j]);
            }

            __builtin_amdgcn_s_setprio(1);
#pragma unroll
            for (int dt = 0; dt < 4; dt++) {
                oacc[qi][dt] = mfma16(vf[dt][0], pf0, oacc[qi][dt]);
                oacc[qi][dt] = mfma16(vf[dt][1], pf1, oacc[qi][dt]);
            }
            den[qi] = mfma16(ones, pf0, den[qi]);
            den[qi] = mfma16(ones, pf1, den[qi]);
            __builtin_amdgcn_s_setprio(0);
        }
    };

    // tile jt (buffer cur=jt%3): stage jt+2, compute jt, counted-wait+barrier
    auto do_tile = [&](int cur, int jt) {
        STAGE((cur + 2) % 3, (jt + 2) * 64);
        COMPUTE(cur);
        asm volatile("s_waitcnt vmcnt(4)" ::: "memory");  // tile jt+1 landed
        __builtin_amdgcn_s_barrier();                     // raw: no vmcnt(0) drain
        asm volatile("" ::: "memory");                    // pin ds_reads after
    };
    auto do_tail = [&](int cur) {                         // tiles 30, 31
        COMPUTE(cur);
        asm volatile("s_waitcnt vmcnt(0)" ::: "memory");
        __builtin_amdgcn_s_barrier();
        asm volatile("" ::: "memory");
    };

    // ---- prologue: stage tiles 0,1; wait tile 0 landed ----
    STAGE(0, 0);
    STAGE(1, 64);
    asm volatile("s_waitcnt vmcnt(4)" ::: "memory");
    __builtin_amdgcn_s_barrier();
    asm volatile("" ::: "memory");

    for (int jt = 0; jt < 30; jt += 3) {
        do_tile(0, jt);
        do_tile(1, jt + 1);
        do_tile(2, jt + 2);
    }
    do_tail(0);   // tile 30
    do_tail(1);   // tile 31

    // ---- normalize + write O (den[qi][0] = full row denominator) ----
#pragma unroll
    for (int qi = 0; qi < 2; qi++) {
        float rinv = 1.0f / den[qi][0];
        size_t rowbase = ((size_t)(b * T_SEQ + q0 + qi * 16 + lr)) * D_MODEL + h * HD;
#pragma unroll
        for (int dt = 0; dt < 4; dt++) {
            ushort4 o;
#pragma unroll
            for (int r = 0; r < 4; r++)
                ((unsigned short*)&o)[r] = f2bf(oacc[qi][dt][r] * rinv);
            *reinterpret_cast<ushort4*>(&O[rowbase + dt * 16 + 4 * grp]) = o;
        }
    }
}

extern "C" void kernel_launch(void* const* d_in, const int* in_sizes, int n_in,
                              void* d_out, int out_size, void* d_ws, size_t ws_size,
                              hipStream_t stream) {
    const float* x  = (const float*)d_in[0];
    const float* Wq = (const float*)d_in[1];
    const float* bq = (const float*)d_in[2];
    const float* Wk = (const float*)d_in[3];
    const float* bk = (const float*)d_in[4];
    const float* Wv = (const float*)d_in[5];
    const float* bv = (const float*)d_in[6];
    const float* Wo = (const float*)d_in[7];
    const float* bo = (const float*)d_in[8];

    char* ws = (char*)d_ws;
    // layout (bytes). Wqt|Wkt|Wvt are ADJACENT -> one fused [1536][1024] Bt.
    unsigned short* xb  = (unsigned short*)(ws);             // 16 MB; reused as O
    unsigned short* Wqt = (unsigned short*)(ws + 16777216);  // 2 MB   (rows 0..1023)
    unsigned short* Wkt = (unsigned short*)(ws + 18874368);  // 0.5 MB (rows 1024..1279)
    unsigned short* Wvt = (unsigned short*)(ws + 19398656);  // 0.5 MB (rows 1280..1535)
    unsigned short* Wot = (unsigned short*)(ws + 19922944);  // 2 MB
    unsigned short* Qb  = (unsigned short*)(ws + 22020096);  // 16 MB
    unsigned short* Kb  = (unsigned short*)(ws + 38797312);  // 4 MB
    unsigned short* Vtb = (unsigned short*)(ws + 42991616);  // 4 MB  (total 45 MB)

    // fused prep: cast x + 4 weight transcasts in ONE launch
    prep<<<dim3(8192 + 2560), 256, 0, stream>>>(
        x, xb, Wq, Wqt, Wk, Wkt, Wv, Wvt, Wo, Wot);

    // fused QKV projection: [8192][1024] @ [1536][1024]^T  (768 blocks, %8==0)
    gemm128<0><<<dim3(12, 64), 256, 0, stream>>>(
        xb, Wqt, bq, bk, bv, Qb, Kb, Vtb, 1024);

    attn_fwd<<<dim3(T_SEQ / 128, NH, BATCH), 256, 0, stream>>>(Qb, Kb, Vtb, xb);

    // output projection -> fp32 d_out  (512 blocks, %8==0)
    gemm128<1><<<dim3(8, 64), 256, 0, stream>>>(
        xb, Wot, bo, nullptr, nullptr, d_out, nullptr, nullptr, 1024);
}

// Round 21
// 157.904 us; speedup vs baseline: 2.0743x; 1.0233x over previous
//
#include <hip/hip_runtime.h>
#include <stdint.h>

#define D_MODEL 1024
#define T_SEQ   2048
#define BATCH   4
#define NH      16
#define NG      4
#define HD      64

// 0.125 * log2(e): folds softmax scale AND exp->exp2 conversion into Q
#define QSCALE 0.18033688611f

typedef short bf16x8 __attribute__((ext_vector_type(8)));
typedef float f32x4  __attribute__((ext_vector_type(4)));

__device__ __forceinline__ f32x4 mfma16(bf16x8 a, bf16x8 b, f32x4 c) {
    return __builtin_amdgcn_mfma_f32_16x16x32_bf16(a, b, c, 0, 0, 0);
}

// HW bf16 convert (RNE)
__device__ __forceinline__ unsigned short f2bf(float f) {
    __bf16 h = (__bf16)f;
    return __builtin_bit_cast(unsigned short, h);
}

// ---------- fused prep: cast x -> bf16 AND 4 weight transpose-casts ----------
__global__ __launch_bounds__(256) void prep(
        const float* __restrict__ x,  unsigned short* __restrict__ xb,
        const float* __restrict__ Wq, unsigned short* __restrict__ Wqt,
        const float* __restrict__ Wk, unsigned short* __restrict__ Wkt,
        const float* __restrict__ Wv, unsigned short* __restrict__ Wvt,
        const float* __restrict__ Wo, unsigned short* __restrict__ Wot) {
    __shared__ unsigned short sh[32][33];
    int bid = blockIdx.x;
    if (bid < 8192) {
        int i = (bid * 256 + threadIdx.x) * 4;
        float4 v = *reinterpret_cast<const float4*>(x + i);
        ushort4 o;
        o.x = f2bf(v.x); o.y = f2bf(v.y); o.z = f2bf(v.z); o.w = f2bf(v.w);
        *reinterpret_cast<ushort4*>(xb + i) = o;
        return;
    }
    bid -= 8192;
    const float* src; unsigned short* dst; int N, nbx;
    if (bid < 1024)      { src = Wq; dst = Wqt; N = 1024; nbx = 32; }
    else if (bid < 1280) { bid -= 1024; src = Wk; dst = Wkt; N = 256;  nbx = 8; }
    else if (bid < 1536) { bid -= 1280; src = Wv; dst = Wvt; N = 256;  nbx = 8; }
    else                 { bid -= 1536; src = Wo; dst = Wot; N = 1024; nbx = 32; }
    const int K = 1024;
    int n0 = (bid % nbx) * 32, k0 = (bid / nbx) * 32;
    int tx = threadIdx.x & 31, ty = threadIdx.x >> 5;   // 32 x 8
#pragma unroll
    for (int j = 0; j < 4; j++) {
        int k = ty + 8 * j;
        sh[k][tx] = f2bf(src[(size_t)(k0 + k) * N + n0 + tx]);
    }
    __syncthreads();
#pragma unroll
    for (int j = 0; j < 4; j++) {
        int n = ty + 8 * j;
        dst[(size_t)(n0 + n) * K + k0 + tx] = sh[tx][n];
    }
}

// ---------- GEMM m97-style: 128x128 tile, BK=64, 4 waves (2x2) ----------
// T1 XCD-aware bijective block swizzle (nwg % 8 == 0 for both launches).
// Hoisted staging offsets; per K-step only +kt is added.
// MODE 0: fused QKV epilogue (Q scaled by QSCALE; K / Vt scatter layouts).
// MODE 1: fp32 row-major out, bias b0.
template <int MODE>
__global__ __launch_bounds__(256) void gemm128(
        const unsigned short* __restrict__ A,
        const unsigned short* __restrict__ Bt,
        const float* __restrict__ b0, const float* __restrict__ b1,
        const float* __restrict__ b2,
        void* __restrict__ Cq, void* __restrict__ Ck, void* __restrict__ Cv,
        int K) {
    __shared__ unsigned short As[128 * 64];
    __shared__ unsigned short Bs[128 * 64];

    int tid  = threadIdx.x;
    int lane = tid & 63, w = tid >> 6;
    int wr = w >> 1, wc = w & 1;

    // ---- T1 XCD swizzle ----
    int nx  = gridDim.x;
    int lin = blockIdx.y * nx + blockIdx.x;
    int cpx = (nx * gridDim.y) >> 3;          // blocks per XCD (nwg % 8 == 0)
    int nb  = (lin & 7) * cpx + (lin >> 3);
    int m0 = (nb / nx) * 128, n0 = (nb % nx) * 128;

    int lr = lane & 15, kg = lane >> 4;

    f32x4 acc[4][4] = {};

    const unsigned short* Ab = A  + (size_t)m0 * K;
    const unsigned short* Bb = Bt + (size_t)n0 * K;

    // ---- hoisted staging offsets (K-loop invariant) ----
    size_t soff[4];
    unsigned short* adst[4];
    unsigned short* bdst[4];
#pragma unroll
    for (int i = 0; i < 4; i++) {
        int ci  = i * 256 + tid;          // chunk index 0..1023
        int row = ci >> 3, ch = ci & 7;
        int csrc = ch ^ (row & 7);
        soff[i] = (size_t)row * K + csrc * 8;
        adst[i] = As + (size_t)(i * 256 + w * 64) * 8;   // wave-uniform
        bdst[i] = Bs + (size_t)(i * 256 + w * 64) * 8;
    }

    for (int kt = 0; kt < K; kt += 64) {
#pragma unroll
        for (int i = 0; i < 4; i++) {
            __builtin_amdgcn_global_load_lds(
                (const __attribute__((address_space(1))) void*)(Ab + soff[i] + kt),
                (__attribute__((address_space(3))) void*)adst[i], 16, 0, 0);
            __builtin_amdgcn_global_load_lds(
                (const __attribute__((address_space(1))) void*)(Bb + soff[i] + kt),
                (__attribute__((address_space(3))) void*)bdst[i], 16, 0, 0);
        }
        __syncthreads();

        bf16x8 af[4][2], bf[4][2];
#pragma unroll
        for (int mt = 0; mt < 4; mt++) {
            int row = wr * 64 + mt * 16 + lr;
#pragma unroll
            for (int ks = 0; ks < 2; ks++) {
                int ch = (kg + ks * 4) ^ (row & 7);
                af[mt][ks] = *reinterpret_cast<const bf16x8*>(&As[row * 64 + ch * 8]);
            }
        }
#pragma unroll
        for (int nt = 0; nt < 4; nt++) {
            int row = wc * 64 + nt * 16 + lr;
#pragma unroll
            for (int ks = 0; ks < 2; ks++) {
                int ch = (kg + ks * 4) ^ (row & 7);
                bf[nt][ks] = *reinterpret_cast<const bf16x8*>(&Bs[row * 64 + ch * 8]);
            }
        }

#pragma unroll
        for (int ks = 0; ks < 2; ks++)
#pragma unroll
            for (int mt = 0; mt < 4; mt++)
#pragma unroll
                for (int nt = 0; nt < 4; nt++)
                    acc[mt][nt] = mfma16(af[mt][ks], bf[nt][ks], acc[mt][nt]);

        __syncthreads();
    }

    // ---- epilogue ----
    int rbase = kg * 4;
#pragma unroll
    for (int nt = 0; nt < 4; nt++) {
        int col = n0 + wc * 64 + nt * 16 + lr;
        float bias;
        if (MODE == 1)            bias = b0[col];
        else if (col < 1024)      bias = b0[col];
        else if (col < 1280)      bias = b1[col - 1024];
        else                      bias = b2[col - 1280];
#pragma unroll
        for (int mt = 0; mt < 4; mt++) {
#pragma unroll
            for (int r = 0; r < 4; r++) {
                int row = m0 + wr * 64 + mt * 16 + rbase + r;
                float v = acc[mt][nt][r] + bias;
                if (MODE == 1) {
                    ((float*)Cq)[(size_t)row * 1024 + col] = v;
                } else if (col < 1024) {
                    ((unsigned short*)Cq)[(size_t)row * 1024 + col] = f2bf(v * QSCALE);
                } else if (col < 1280) {
                    int cc = col - 1024, g = cc >> 6, d = cc & 63;
                    int b = row >> 11, t = row & 2047;
                    ((unsigned short*)Ck)[(((size_t)(b * NG + g)) * T_SEQ + t) * HD + d] = f2bf(v);
                } else {
                    int cc = col - 1280, g = cc >> 6, d = cc & 63;
                    int b = row >> 11, t = row & 2047;
                    ((unsigned short*)Cv)[(((size_t)(b * NG + g)) * HD + d) * T_SEQ + t] = f2bf(v);
                }
            }
        }
    }
}

// ---------- flash attention v18: pair-ping-pong, 2 tiles per barrier ----------
// v16 bodies (kperm'd K staging, lane-local P, b128 V reads, hoisted offsets,
// ones-MFMA denominator) with the sync restructured:
//   4 buffers in 2 PAIRS (64 KB). Interval i: issue stages for tiles
//   2i+2, 2i+3 into the pair NOT being read (loads get a full 2-tile
//   ~1100 cy window, covering ~900 cy HBM miss latency), compute tiles
//   2i, 2i+1 from the current pair, then ONE vmcnt(0) (near-free: its
//   loads were issued an interval ago) + ONE raw s_barrier.
// Halves barrier count 32 -> 16 and makes every drain non-blocking.
// Buffer safety: stages write the pair whose readers passed the previous
// barrier. Risk accepted: LDS 48->64 KB (2 blocks/CU) -- measured
// occupancy ~19% (~6 waves/CU) suggests the 3rd block wasn't helping.
__global__ __launch_bounds__(256) void attn_fwd(
        const unsigned short* __restrict__ Q,
        const unsigned short* __restrict__ Kt,
        const unsigned short* __restrict__ Vt,
        unsigned short* __restrict__ O) {
    int tid  = threadIdx.x;
    int lane = tid & 63;
    int w    = tid >> 6;
    int qt = blockIdx.x, h = blockIdx.y, b = blockIdx.z;
    int g = h >> 2;                 // HPG = 4
    int lr  = lane & 15;
    int grp = lane >> 4;
    int ko  = grp * 8;
    int q0  = qt * 128 + w * 32;

    __shared__ unsigned short Kl[4][64 * 64];
    __shared__ unsigned short Vl[4][64 * 64];

    const unsigned short* Kp = Kt + ((size_t)(b * NG + g)) * T_SEQ * HD;
    const unsigned short* Vp = Vt + ((size_t)(b * NG + g)) * HD * T_SEQ;

    bf16x8 qf[2][2];
#pragma unroll
    for (int qi = 0; qi < 2; qi++) {
        const unsigned short* Qp =
            Q + ((size_t)(b * T_SEQ + q0 + qi * 16 + lr)) * D_MODEL + h * HD;
        qf[qi][0] = *reinterpret_cast<const bf16x8*>(Qp + ko);
        qf[qi][1] = *reinterpret_cast<const bf16x8*>(Qp + 32 + ko);
    }

    f32x4 oacc[2][4] = {};    // [qi][dt] : O^T, col=q=lr, row=d=dt*16+4grp+reg
    f32x4 den[2] = {};        // ones-MFMA denominator
    bf16x8 ones;
#pragma unroll
    for (int j = 0; j < 8; j++) ones[j] = (short)0x3F80;   // bf16 1.0

    // ---- hoisted LDS read offsets (elements); same formula for K and V ----
    int loff[4][2];
#pragma unroll
    for (int c = 0; c < 4; c++) {
        int row = c * 16 + lr;
#pragma unroll
        for (int s = 0; s < 2; s++)
            loff[c][s] = row * 64 + (((s * 4 + grp) ^ (row & 7)) * 8);
    }

    // ---- hoisted STAGE global bases + LDS dest offset ----
    const unsigned short* gkb[2];
    const unsigned short* gvb[2];
    size_t lkd[2];
#pragma unroll
    for (int i = 0; i < 2; i++) {
        int ci  = i * 256 + tid;          // chunk 0..511
        int row = ci >> 3, ch = ci & 7;
        int csrc = ch ^ (row & 7);
        int kp = 32 * (row >> 5) + 4 * ((row >> 4) & 1)
               + 8 * ((row >> 2) & 3) + (row & 3);
        gkb[i] = Kp + (size_t)kp * HD + csrc * 8;
        gvb[i] = Vp + (size_t)row * T_SEQ + csrc * 8;
        lkd[i] = (size_t)(i * 256 + w * 64) * 8;  // elem offset within buffer
    }

    auto STAGE = [&](int buf, int j0) {   // buf literal at every call site
#pragma unroll
        for (int i = 0; i < 2; i++) {
            __builtin_amdgcn_global_load_lds(
                (const __attribute__((address_space(1))) void*)(gkb[i] + ((size_t)j0 << 6)),
                (__attribute__((address_space(3))) void*)(&Kl[buf][0] + lkd[i]), 16, 0, 0);
            __builtin_amdgcn_global_load_lds(
                (const __attribute__((address_space(1))) void*)(gvb[i] + j0),
                (__attribute__((address_space(3))) void*)(&Vl[buf][0] + lkd[i]), 16, 0, 0);
        }
    };

    // ---- compute body for tile in buffer `cur` (literal) ----
    auto COMPUTE = [&](int cur) {
        const unsigned short* kb = &Kl[cur][0];
        const unsigned short* vb = &Vl[cur][0];

        bf16x8 kf[4][2], vf[4][2];
#pragma unroll
        for (int t = 0; t < 4; t++)
#pragma unroll
            for (int ks = 0; ks < 2; ks++)
                kf[t][ks] = *reinterpret_cast<const bf16x8*>(kb + loff[t][ks]);
#pragma unroll
        for (int dt = 0; dt < 4; dt++)
#pragma unroll
            for (int kh = 0; kh < 2; kh++)
                vf[dt][kh] = *reinterpret_cast<const bf16x8*>(vb + loff[dt][kh]);

#pragma unroll
        for (int qi = 0; qi < 2; qi++) {
            f32x4 s[4];
            __builtin_amdgcn_s_setprio(1);
#pragma unroll
            for (int t = 0; t < 4; t++) {
                f32x4 a = {};
                a = mfma16(kf[t][0], qf[qi][0], a);
                a = mfma16(kf[t][1], qf[qi][1], a);
                s[t] = a;   // s[t][r] = S[key=32(t>>1)+4(t&1)+8grp+r][q=lr]
            }
            __builtin_amdgcn_s_setprio(0);

            float p[4][4];
#pragma unroll
            for (int t = 0; t < 4; t++)
#pragma unroll
                for (int r = 0; r < 4; r++)
                    asm("v_exp_f32 %0, %1" : "=v"(p[t][r]) : "v"(s[t][r]));

            bf16x8 pf0, pf1;
#pragma unroll
            for (int j = 0; j < 4; j++) {
                pf0[j]     = (short)f2bf(p[0][j]);
                pf0[j + 4] = (short)f2bf(p[1][j]);
                pf1[j]     = (short)f2bf(p[2][j]);
                pf1[j + 4] = (short)f2bf(p[3][j]);
            }

            __builtin_amdgcn_s_setprio(1);
#pragma unroll
            for (int dt = 0; dt < 4; dt++) {
                oacc[qi][dt] = mfma16(vf[dt][0], pf0, oacc[qi][dt]);
                oacc[qi][dt] = mfma16(vf[dt][1], pf1, oacc[qi][dt]);
            }
            den[qi] = mfma16(ones, pf0, den[qi]);
            den[qi] = mfma16(ones, pf1, den[qi]);
            __builtin_amdgcn_s_setprio(0);
        }
    };

    // ---- interval: stage next pair (if any), compute 2 tiles, 1 sync ----
    // pb = literal pair base (0 or 2); it = interval index (0..15)
    auto INTERVAL = [&](int pb, int it) {
        if (it < 15) {
            STAGE(pb ^ 2, (2 * it + 2) * 64);
            STAGE((pb ^ 2) | 1, (2 * it + 3) * 64);
        }
        COMPUTE(pb);
        COMPUTE(pb | 1);
        asm volatile("s_waitcnt vmcnt(0)" ::: "memory");
        __builtin_amdgcn_s_barrier();
        asm volatile("" ::: "memory");
    };

    // ---- prologue: stage tiles 0,1 into pair 0 ----
    STAGE(0, 0);
    STAGE(1, 64);
    asm volatile("s_waitcnt vmcnt(0)" ::: "memory");
    __builtin_amdgcn_s_barrier();
    asm volatile("" ::: "memory");

    for (int it = 0; it < 16; it += 2) {
        INTERVAL(0, it);       // pair 0: bufs 0,1
        INTERVAL(2, it + 1);   // pair 1: bufs 2,3
    }

    // ---- normalize + write O (den[qi][0] = full row denominator) ----
#pragma unroll
    for (int qi = 0; qi < 2; qi++) {
        float rinv = 1.0f / den[qi][0];
        size_t rowbase = ((size_t)(b * T_SEQ + q0 + qi * 16 + lr)) * D_MODEL + h * HD;
#pragma unroll
        for (int dt = 0; dt < 4; dt++) {
            ushort4 o;
#pragma unroll
            for (int r = 0; r < 4; r++)
                ((unsigned short*)&o)[r] = f2bf(oacc[qi][dt][r] * rinv);
            *reinterpret_cast<ushort4*>(&O[rowbase + dt * 16 + 4 * grp]) = o;
        }
    }
}

extern "C" void kernel_launch(void* const* d_in, const int* in_sizes, int n_in,
                              void* d_out, int out_size, void* d_ws, size_t ws_size,
                              hipStream_t stream) {
    const float* x  = (const float*)d_in[0];
    const float* Wq = (const float*)d_in[1];
    const float* bq = (const float*)d_in[2];
    const float* Wk = (const float*)d_in[3];
    const float* bk = (const float*)d_in[4];
    const float* Wv = (const float*)d_in[5];
    const float* bv = (const float*)d_in[6];
    const float* Wo = (const float*)d_in[7];
    const float* bo = (const float*)d_in[8];

    char* ws = (char*)d_ws;
    // layout (bytes). Wqt|Wkt|Wvt are ADJACENT -> one fused [1536][1024] Bt.
    unsigned short* xb  = (unsigned short*)(ws);             // 16 MB; reused as O
    unsigned short* Wqt = (unsigned short*)(ws + 16777216);  // 2 MB   (rows 0..1023)
    unsigned short* Wkt = (unsigned short*)(ws + 18874368);  // 0.5 MB (rows 1024..1279)
    unsigned short* Wvt = (unsigned short*)(ws + 19398656);  // 0.5 MB (rows 1280..1535)
    unsigned short* Wot = (unsigned short*)(ws + 19922944);  // 2 MB
    unsigned short* Qb  = (unsigned short*)(ws + 22020096);  // 16 MB
    unsigned short* Kb  = (unsigned short*)(ws + 38797312);  // 4 MB
    unsigned short* Vtb = (unsigned short*)(ws + 42991616);  // 4 MB  (total 45 MB)

    // fused prep: cast x + 4 weight transcasts in ONE launch
    prep<<<dim3(8192 + 2560), 256, 0, stream>>>(
        x, xb, Wq, Wqt, Wk, Wkt, Wv, Wvt, Wo, Wot);

    // fused QKV projection: [8192][1024] @ [1536][1024]^T  (768 blocks, %8==0)
    gemm128<0><<<dim3(12, 64), 256, 0, stream>>>(
        xb, Wqt, bq, bk, bv, Qb, Kb, Vtb, 1024);

    attn_fwd<<<dim3(T_SEQ / 128, NH, BATCH), 256, 0, stream>>>(Qb, Kb, Vtb, xb);

    // output projection -> fp32 d_out  (512 blocks, %8==0)
    gemm128<1><<<dim3(8, 64), 256, 0, stream>>>(
        xb, Wot, bo, nullptr, nullptr, d_out, nullptr, nullptr, 1024);
}